// Round 2
// baseline (2247.056 us; speedup 1.0000x reference)
//
#include <hip/hip_runtime.h>

// ---------------------------------------------------------------------------
// GCKAN (3 layers) on MI355X — round 4: pre-gathered, pre-tiled bf16 EA.
// Round-3 edge kernels were latency-bound on the random-row f32 EA gather
// (sorted eid order): 14% HBM, 6.5% MFMA, nothing busy. Now a single
// streaming pass gathers EA into sorted order, converts to bf16, and lays it
// out in the exact per-K-step LDS staging layout. Edge kernels become pure
// linear streams with register prefetch of the next K-step.
// ---------------------------------------------------------------------------

typedef __attribute__((ext_vector_type(4))) float f32x4;
typedef __attribute__((ext_vector_type(8))) short bf16x8;
typedef __attribute__((ext_vector_type(8))) unsigned short u16x8;
typedef __attribute__((ext_vector_type(4))) unsigned short u16x4;

__device__ __forceinline__ unsigned short f2bf(float f) {
    union { float f; unsigned u; } v; v.f = f;
    unsigned r = v.u + 0x7FFFu + ((v.u >> 16) & 1u);
    return (unsigned short)(r >> 16);
}

__device__ __forceinline__ float siluf(float x) {
    return x / (1.0f + __expf(-x));
}

// Expand scalar x -> 8 channels [silu, B0..B6]; cubic B-spline on uniform
// knots t_i = 0.5 i - 2.5 (matches reference Cox-de Boor exactly).
__device__ __forceinline__ void expand8(float x, float* o8) {
    float b[10];
#pragma unroll
    for (int i = 0; i < 10; ++i) {
        float ti = 0.5f * i - 2.5f;
        b[i] = (x >= ti && x < ti + 0.5f) ? 1.0f : 0.0f;
    }
#pragma unroll
    for (int j = 1; j <= 3; ++j) {
        float inv = 2.0f / (float)j;
#pragma unroll
        for (int i = 0; i < 10 - j; ++i) {
            float ti = 0.5f * i - 2.5f;
            float tj = 0.5f * (i + j + 1) - 2.5f;
            b[i] = (x - ti) * inv * b[i] + (tj - x) * inv * b[i + 1];
        }
    }
    o8[0] = siluf(x);
#pragma unroll
    for (int c = 0; c < 7; ++c) o8[c + 1] = b[c];
}

// ---------------------------------------------------------------------------
// Edge counting sort by destination (col).
// ---------------------------------------------------------------------------
__global__ __launch_bounds__(256) void k_hist(
    const int* __restrict__ col, int* __restrict__ cnt, int E) {
    int i = blockIdx.x * 256 + threadIdx.x;
    if (i < E) atomicAdd(&cnt[col[i]], 1);
}

__global__ __launch_bounds__(1024) void k_scan(int* __restrict__ c, int N) {
    __shared__ int wsum[16];
    __shared__ int ctot;
    const int t = threadIdx.x;
    const int lane = t & 63, wid = t >> 6;
    int carry = 0;
    for (int base = 0; base < N; base += 1024) {
        int i = base + t;
        int v0 = (i < N) ? c[i] : 0;
        int v = v0;
#pragma unroll
        for (int off = 1; off < 64; off <<= 1) {
            int n = __shfl_up(v, (unsigned)off, 64);
            if (lane >= off) v += n;
        }
        if (lane == 63) wsum[wid] = v;
        __syncthreads();
        if (t < 16) {
            int s = wsum[t], sv = s;
#pragma unroll
            for (int off = 1; off < 16; off <<= 1) {
                int n = __shfl_up(sv, (unsigned)off, 16);
                if (t >= off) sv += n;
            }
            wsum[t] = sv - s;
            if (t == 15) ctot = sv;
        }
        __syncthreads();
        if (i < N) c[i] = carry + wsum[wid] + v - v0;
        carry += ctot;
        __syncthreads();
    }
}

__global__ __launch_bounds__(256) void k_scatter(
    const int* __restrict__ row, const int* __restrict__ col,
    int* __restrict__ cursor, int* __restrict__ rowS,
    int* __restrict__ eidS, int* __restrict__ colS, int E) {
    int i = blockIdx.x * 256 + threadIdx.x;
    if (i < E) {
        int c = col[i];
        int p = atomicAdd(&cursor[c], 1);
        rowS[p] = row[i];
        eidS[p] = i;
        colS[p] = c;
    }
}

// ---------------------------------------------------------------------------
// Gather EA rows into sorted order, bf16, PRE-TILED in LDS staging layout:
// tile t (64 edges) = 24576 u16; within: [it=0..11][g=0..3][r=0..63][c=0..7]
// element (p = t*64+r, k = it*32+g*8+c).  One wave handles one edge row
// (48 active lanes, 1.5KB coalesced read); a block's 4 waves fill complete
// 64B lines on the write side.
// ---------------------------------------------------------------------------
__global__ __launch_bounds__(256) void gather_ea(
    const float* __restrict__ EA, const int* __restrict__ eidS,
    unsigned short* __restrict__ EAs, int E, int Epad) {
    long idx = (long)blockIdx.x * 256 + threadIdx.x;   // = p*64 + l
    int l = (int)(idx & 63);
    long p = idx >> 6;
    if (p >= Epad || l >= 48) return;
    u16x8 o = {};
    if (p < E) {
        const float* src = EA + (long)eidS[p] * 384 + l * 8;
        float4 v0 = *(const float4*)src;
        float4 v1 = *(const float4*)(src + 4);
        o[0] = f2bf(v0.x); o[1] = f2bf(v0.y); o[2] = f2bf(v0.z); o[3] = f2bf(v0.w);
        o[4] = f2bf(v1.x); o[5] = f2bf(v1.y); o[6] = f2bf(v1.z); o[7] = f2bf(v1.w);
    }
    long t = p >> 6;
    int r = (int)(p & 63);
    int it = l >> 2, g = l & 3;
    *(u16x8*)(EAs + t * 24576 + it * 2048 + g * 512 + r * 8) = o;
}

// ---------------------------------------------------------------------------
// Fused edge layer N=256 on pre-tiled sorted bf16 EA.
// Tile: 64 sorted edges x 256 outs, 4 waves, K-step 32, register prefetch.
// ---------------------------------------------------------------------------
__global__ __launch_bounds__(256) void edge_mfma256_p(
    const unsigned short* __restrict__ EAs, const unsigned short* __restrict__ Wh,
    const float* __restrict__ eb, const float* __restrict__ XT,
    const int* __restrict__ rowS, const int* __restrict__ colS,
    float* __restrict__ AGG, int E) {
    __shared__ __align__(16) char smem[64 * 130 * 4];   // 33280 B
    unsigned short (*As)[64][8]  = (unsigned short (*)[64][8])smem;           // 4 KB
    unsigned short (*Bs)[256][8] = (unsigned short (*)[256][8])(smem + 4096); // 16 KB
    float (*MSG)[130] = (float (*)[130])smem;            // union, after K loop
    __shared__ int cols_s[64];
    __shared__ int runst[65];
    __shared__ int runc[64];
    __shared__ int nruns;

    const int tid = threadIdx.x;
    const int wv = tid >> 6, lane = tid & 63;
    const int l15 = lane & 15, l4 = lane >> 4;
    const long m0 = (long)blockIdx.x * 64;
    f32x4 acc[4][4] = {};

    const u16x8* srcA = (const u16x8*)(EAs + (long)blockIdx.x * 24576);
    const unsigned short* bptr = Wh + (long)tid * 384;

    // register prefetch of K-step 0
    u16x8 ap = srcA[tid];
    u16x8 bb0 = *(const u16x8*)(bptr + 0);
    u16x8 bb1 = *(const u16x8*)(bptr + 8);
    u16x8 bb2 = *(const u16x8*)(bptr + 16);
    u16x8 bb3 = *(const u16x8*)(bptr + 24);

    // ---- run table (cols globally non-decreasing) ----
    if (tid < 64) {
        long p = m0 + tid;
        cols_s[tid] = (p < E) ? colS[p] : -1;
    }
    __syncthreads();
    if (tid == 0) {
        int nr = 0, prev = -2;
        for (int e = 0; e < 64; ++e) {
            int cc = cols_s[e];
            if (cc != prev) { runst[nr] = e; runc[nr] = cc; prev = cc; ++nr; }
        }
        runst[nr] = 64;
        nruns = nr;
    }

    for (int it = 0; it < 12; ++it) {
        __syncthreads();
        ((u16x8*)As)[tid] = ap;       // flat copy == [g][r][8] layout
        *(u16x8*)&Bs[0][tid][0] = bb0;
        *(u16x8*)&Bs[1][tid][0] = bb1;
        *(u16x8*)&Bs[2][tid][0] = bb2;
        *(u16x8*)&Bs[3][tid][0] = bb3;
        __syncthreads();
        if (it < 11) {                // prefetch next K-step under MFMA
            const int k0 = (it + 1) * 32;
            ap  = srcA[(it + 1) * 256 + tid];
            bb0 = *(const u16x8*)(bptr + k0);
            bb1 = *(const u16x8*)(bptr + k0 + 8);
            bb2 = *(const u16x8*)(bptr + k0 + 16);
            bb3 = *(const u16x8*)(bptr + k0 + 24);
        }
        bf16x8 af[4], bfv[4];
#pragma unroll
        for (int mi = 0; mi < 4; ++mi)
            af[mi] = *(const bf16x8*)&As[l4][mi * 16 + l15][0];
#pragma unroll
        for (int nj = 0; nj < 4; ++nj)
            bfv[nj] = *(const bf16x8*)&Bs[l4][wv * 64 + nj * 16 + l15][0];
#pragma unroll
        for (int mi = 0; mi < 4; ++mi)
#pragma unroll
            for (int nj = 0; nj < 4; ++nj)
                acc[mi][nj] = __builtin_amdgcn_mfma_f32_16x16x32_bf16(
                    af[mi], bfv[nj], acc[mi][nj], 0, 0, 0);
    }

    const int nb = wv * 64;
    float bs[4];
#pragma unroll
    for (int nj = 0; nj < 4; ++nj) bs[nj] = eb[nb + nj * 16 + l15];

#pragma unroll
    for (int p = 0; p < 2; ++p) {
        __syncthreads();
        if ((wv >> 1) == p) {
            const int cb = nb - p * 128;
#pragma unroll
            for (int mi = 0; mi < 4; ++mi) {
#pragma unroll
                for (int r = 0; r < 4; ++r) {
                    long e = m0 + mi * 16 + l4 * 4 + r;
                    if (e < E) {
                        int rn = rowS[e];
                        const float* xr = XT + (long)rn * 256 + nb + l15;
                        float* mrow = &MSG[mi * 16 + l4 * 4 + r][cb + l15];
#pragma unroll
                        for (int nj = 0; nj < 4; ++nj)
                            mrow[nj * 16] = (acc[mi][nj][r] + bs[nj]) * xr[nj * 16];
                    }
                }
            }
        }
        __syncthreads();
        const int colv = tid & 127, g = tid >> 7;
        const int nr = nruns;
        for (int ri = g; ri < nr; ri += 2) {
            int cc = runc[ri];
            if (cc < 0) continue;
            int a = runst[ri], b = runst[ri + 1];
            float s = 0.f;
            for (int e = a; e < b; ++e) s += MSG[e][colv];
            float* dst = AGG + (long)cc * 256 + p * 128 + colv;
            if (a > 0 && b < 64) *dst = s;
            else atomicAdd(dst, s);
        }
    }
}

// ---------------------------------------------------------------------------
// Fused edge layer N=32 on pre-tiled sorted bf16 EA.
// Tile 256 sorted edges (= 4 consecutive 64-tiles) x 32 outs.
// ---------------------------------------------------------------------------
__global__ __launch_bounds__(256) void edge_mfma32_p(
    const unsigned short* __restrict__ EAs, const unsigned short* __restrict__ Wh,
    const float* __restrict__ eb, const float* __restrict__ XT,
    const int* __restrict__ rowS, const int* __restrict__ colS,
    float* __restrict__ AGG, int E) {
    __shared__ __align__(16) char smem[256 * 34 * 4];   // 34816 B
    unsigned short (*As2)[4][64][8] = (unsigned short (*)[4][64][8])smem;       // 16 KB
    unsigned short (*Bs)[32][8]     = (unsigned short (*)[32][8])(smem + 16384); // 2 KB
    float (*MSG)[34] = (float (*)[34])smem;
    __shared__ int cols_s[256];
    __shared__ int runst[257];
    __shared__ int runc[256];
    __shared__ int nruns;

    const int tid = threadIdx.x;
    const int wv = tid >> 6, lane = tid & 63;
    const int l15 = lane & 15, l4 = lane >> 4;
    const long m0 = (long)blockIdx.x * 256;
    const long t0 = (long)blockIdx.x * 4;
    f32x4 acc[4][2] = {};

    const u16x8* baseq[4];
#pragma unroll
    for (int q = 0; q < 4; ++q)
        baseq[q] = (const u16x8*)(EAs + (t0 + q) * 24576);
    const unsigned short* bp = Wh + (long)(tid >> 2) * 384 + (tid & 3) * 8;

    u16x8 aq[4];
#pragma unroll
    for (int q = 0; q < 4; ++q) aq[q] = baseq[q][tid];
    u16x8 bv = {};
    if (tid < 128) bv = *(const u16x8*)bp;

    {
        long p = m0 + tid;
        cols_s[tid] = (p < E) ? colS[p] : -1;
    }
    __syncthreads();
    if (tid == 0) {
        int nr = 0, prev = -2;
        for (int e = 0; e < 256; ++e) {
            int cc = cols_s[e];
            if (cc != prev) { runst[nr] = e; runc[nr] = cc; prev = cc; ++nr; }
        }
        runst[nr] = 256;
        nruns = nr;
    }

    for (int it = 0; it < 12; ++it) {
        __syncthreads();
#pragma unroll
        for (int q = 0; q < 4; ++q)
            ((u16x8*)As2)[q * 256 + tid] = aq[q];
        if (tid < 128) *(u16x8*)&Bs[tid & 3][tid >> 2][0] = bv;
        __syncthreads();
        if (it < 11) {
            const int o8 = (it + 1) * 256;
#pragma unroll
            for (int q = 0; q < 4; ++q) aq[q] = baseq[q][o8 + tid];
            if (tid < 128) bv = *(const u16x8*)(bp + (it + 1) * 32);
        }
        bf16x8 af[4], bfv[2];
#pragma unroll
        for (int mi = 0; mi < 4; ++mi)
            af[mi] = *(const bf16x8*)&As2[wv][l4][mi * 16 + l15][0];
#pragma unroll
        for (int nj = 0; nj < 2; ++nj)
            bfv[nj] = *(const bf16x8*)&Bs[l4][nj * 16 + l15][0];
#pragma unroll
        for (int mi = 0; mi < 4; ++mi)
#pragma unroll
            for (int nj = 0; nj < 2; ++nj)
                acc[mi][nj] = __builtin_amdgcn_mfma_f32_16x16x32_bf16(
                    af[mi], bfv[nj], acc[mi][nj], 0, 0, 0);
    }

    float bs2[2];
#pragma unroll
    for (int nj = 0; nj < 2; ++nj) bs2[nj] = eb[nj * 16 + l15];

    __syncthreads();
#pragma unroll
    for (int mi = 0; mi < 4; ++mi) {
#pragma unroll
        for (int r = 0; r < 4; ++r) {
            int el = wv * 64 + mi * 16 + l4 * 4 + r;
            long e = m0 + el;
            if (e < E) {
                int rn = rowS[e];
#pragma unroll
                for (int nj = 0; nj < 2; ++nj) {
                    int o = nj * 16 + l15;
                    MSG[el][o] = (acc[mi][nj][r] + bs2[nj]) * XT[(long)rn * 32 + o];
                }
            }
        }
    }
    __syncthreads();
    const int colv = tid & 31, g = tid >> 5;
    const int nr = nruns;
    for (int ri = g; ri < nr; ri += 8) {
        int cc = runc[ri];
        if (cc < 0) continue;
        int a = runst[ri], b = runst[ri + 1];
        float s = 0.f;
        for (int e = a; e < b; ++e) s += MSG[e][colv];
        float* dst = AGG + (long)cc * 32 + colv;
        if (a > 0 && b < 256) *dst = s;
        else atomicAdd(dst, s);
    }
}

// ---------------------------------------------------------------------------
// FALLBACK edge kernels (workspace too small for EAs): round-3 versions.
// ---------------------------------------------------------------------------
__global__ __launch_bounds__(256) void edge_mfma256_s(
    const float* __restrict__ EA, const unsigned short* __restrict__ Wh,
    const float* __restrict__ eb, const float* __restrict__ XT,
    const int* __restrict__ rowS, const int* __restrict__ colS,
    const int* __restrict__ eidS, float* __restrict__ AGG, int E) {
    __shared__ __align__(16) char smem[64 * 130 * 4];
    unsigned short (*As)[64][8]  = (unsigned short (*)[64][8])smem;
    unsigned short (*Bs)[256][8] = (unsigned short (*)[256][8])(smem + 4096);
    float (*MSG)[130] = (float (*)[130])smem;
    __shared__ int cols_s[64];
    __shared__ int runst[65];
    __shared__ int runc[64];
    __shared__ int nruns;

    const int tid = threadIdx.x;
    const int wv = tid >> 6, lane = tid & 63;
    const int l15 = lane & 15, l4 = lane >> 4;
    const long m0 = (long)blockIdx.x * 64;
    f32x4 acc[4][4] = {};

    if (tid < 64) {
        long p = m0 + tid;
        cols_s[tid] = (p < E) ? colS[p] : -1;
    }
    __syncthreads();
    if (tid == 0) {
        int nr = 0, prev = -2;
        for (int e = 0; e < 64; ++e) {
            int cc = cols_s[e];
            if (cc != prev) { runst[nr] = e; runc[nr] = cc; prev = cc; ++nr; }
        }
        runst[nr] = 64;
        nruns = nr;
    }

    const int sr = tid >> 2;
    const int sg = tid & 3;
    const long arow = m0 + sr;
    const bool aok = arow < E;
    const long eid = aok ? (long)eidS[arow] : 0;
    const float* aptr = EA + eid * 384 + sg * 8;
    const unsigned short* bptr = Wh + (long)tid * 384;

    for (int it = 0; it < 12; ++it) {
        const int k0 = it * 32;
        u16x8 ap = {};
        if (aok) {
            float4 v0 = *(const float4*)(aptr + k0);
            float4 v1 = *(const float4*)(aptr + k0 + 4);
            ap[0] = f2bf(v0.x); ap[1] = f2bf(v0.y); ap[2] = f2bf(v0.z); ap[3] = f2bf(v0.w);
            ap[4] = f2bf(v1.x); ap[5] = f2bf(v1.y); ap[6] = f2bf(v1.z); ap[7] = f2bf(v1.w);
        }
        u16x8 b0 = *(const u16x8*)(bptr + k0);
        u16x8 b1 = *(const u16x8*)(bptr + k0 + 8);
        u16x8 b2 = *(const u16x8*)(bptr + k0 + 16);
        u16x8 b3 = *(const u16x8*)(bptr + k0 + 24);
        __syncthreads();
        *(u16x8*)&As[sg][sr][0] = ap;
        *(u16x8*)&Bs[0][tid][0] = b0;
        *(u16x8*)&Bs[1][tid][0] = b1;
        *(u16x8*)&Bs[2][tid][0] = b2;
        *(u16x8*)&Bs[3][tid][0] = b3;
        __syncthreads();
        bf16x8 af[4], bfv[4];
#pragma unroll
        for (int mi = 0; mi < 4; ++mi)
            af[mi] = *(const bf16x8*)&As[l4][mi * 16 + l15][0];
#pragma unroll
        for (int nj = 0; nj < 4; ++nj)
            bfv[nj] = *(const bf16x8*)&Bs[l4][wv * 64 + nj * 16 + l15][0];
#pragma unroll
        for (int mi = 0; mi < 4; ++mi)
#pragma unroll
            for (int nj = 0; nj < 4; ++nj)
                acc[mi][nj] = __builtin_amdgcn_mfma_f32_16x16x32_bf16(
                    af[mi], bfv[nj], acc[mi][nj], 0, 0, 0);
    }

    const int nb = wv * 64;
    float bs[4];
#pragma unroll
    for (int nj = 0; nj < 4; ++nj) bs[nj] = eb[nb + nj * 16 + l15];

#pragma unroll
    for (int p = 0; p < 2; ++p) {
        __syncthreads();
        if ((wv >> 1) == p) {
            const int cb = nb - p * 128;
#pragma unroll
            for (int mi = 0; mi < 4; ++mi) {
#pragma unroll
                for (int r = 0; r < 4; ++r) {
                    long e = m0 + mi * 16 + l4 * 4 + r;
                    if (e < E) {
                        int rn = rowS[e];
                        const float* xr = XT + (long)rn * 256 + nb + l15;
                        float* mrow = &MSG[mi * 16 + l4 * 4 + r][cb + l15];
#pragma unroll
                        for (int nj = 0; nj < 4; ++nj)
                            mrow[nj * 16] = (acc[mi][nj][r] + bs[nj]) * xr[nj * 16];
                    }
                }
            }
        }
        __syncthreads();
        const int colv = tid & 127, g = tid >> 7;
        const int nr = nruns;
        for (int ri = g; ri < nr; ri += 2) {
            int cc = runc[ri];
            if (cc < 0) continue;
            int a = runst[ri], b = runst[ri + 1];
            float s = 0.f;
            for (int e = a; e < b; ++e) s += MSG[e][colv];
            float* dst = AGG + (long)cc * 256 + p * 128 + colv;
            if (a > 0 && b < 64) *dst = s;
            else atomicAdd(dst, s);
        }
    }
}

__global__ __launch_bounds__(256) void edge_mfma32_s(
    const float* __restrict__ EA, const unsigned short* __restrict__ Wh,
    const float* __restrict__ eb, const float* __restrict__ XT,
    const int* __restrict__ rowS, const int* __restrict__ colS,
    const int* __restrict__ eidS, float* __restrict__ AGG, int E) {
    __shared__ __align__(16) char smem[256 * 34 * 4];
    unsigned short (*As)[256][8] = (unsigned short (*)[256][8])smem;
    unsigned short (*Bs)[32][8]  = (unsigned short (*)[32][8])(smem + 16384);
    float (*MSG)[34] = (float (*)[34])smem;
    __shared__ int cols_s[256];
    __shared__ int runst[257];
    __shared__ int runc[256];
    __shared__ int nruns;

    const int tid = threadIdx.x;
    const int wv = tid >> 6, lane = tid & 63;
    const int l15 = lane & 15, l4 = lane >> 4;
    const long m0 = (long)blockIdx.x * 256;
    f32x4 acc[4][2] = {};

    {
        long p = m0 + tid;
        cols_s[tid] = (p < E) ? colS[p] : -1;
    }
    __syncthreads();
    if (tid == 0) {
        int nr = 0, prev = -2;
        for (int e = 0; e < 256; ++e) {
            int cc = cols_s[e];
            if (cc != prev) { runst[nr] = e; runc[nr] = cc; prev = cc; ++nr; }
        }
        runst[nr] = 256;
        nruns = nr;
    }

    const int sr = tid >> 3;
    const int sq = (tid & 7) * 4;
    const int sg2 = sq >> 3, so2 = sq & 7;

    int eidv[8];
#pragma unroll
    for (int j = 0; j < 8; ++j) {
        long p = m0 + j * 32 + sr;
        eidv[j] = (p < E) ? eidS[p] : -1;
    }

    for (int it = 0; it < 12; ++it) {
        const int k0 = it * 32;
        float4 va[8];
#pragma unroll
        for (int j = 0; j < 8; ++j)
            va[j] = (eidv[j] >= 0) ? *(const float4*)(EA + (long)eidv[j] * 384 + k0 + sq)
                                   : make_float4(0.f, 0.f, 0.f, 0.f);
        u16x8 bv = {};
        if (tid < 128)
            bv = *(const u16x8*)(Wh + (long)(tid >> 2) * 384 + k0 + (tid & 3) * 8);
        __syncthreads();
#pragma unroll
        for (int j = 0; j < 8; ++j) {
            u16x4 ap;
            ap[0] = f2bf(va[j].x); ap[1] = f2bf(va[j].y);
            ap[2] = f2bf(va[j].z); ap[3] = f2bf(va[j].w);
            *(u16x4*)&As[sg2][j * 32 + sr][so2] = ap;
        }
        if (tid < 128) *(u16x8*)&Bs[tid & 3][tid >> 2][0] = bv;
        __syncthreads();
        bf16x8 af[4], bfv[2];
#pragma unroll
        for (int mi = 0; mi < 4; ++mi)
            af[mi] = *(const bf16x8*)&As[l4][wv * 64 + mi * 16 + l15][0];
#pragma unroll
        for (int nj = 0; nj < 2; ++nj)
            bfv[nj] = *(const bf16x8*)&Bs[l4][nj * 16 + l15][0];
#pragma unroll
        for (int mi = 0; mi < 4; ++mi)
#pragma unroll
            for (int nj = 0; nj < 2; ++nj)
                acc[mi][nj] = __builtin_amdgcn_mfma_f32_16x16x32_bf16(
                    af[mi], bfv[nj], acc[mi][nj], 0, 0, 0);
    }

    float bs2[2];
#pragma unroll
    for (int nj = 0; nj < 2; ++nj) bs2[nj] = eb[nj * 16 + l15];

    __syncthreads();
#pragma unroll
    for (int mi = 0; mi < 4; ++mi) {
#pragma unroll
        for (int r = 0; r < 4; ++r) {
            int el = wv * 64 + mi * 16 + l4 * 4 + r;
            long e = m0 + el;
            if (e < E) {
                int rn = rowS[e];
#pragma unroll
                for (int nj = 0; nj < 2; ++nj) {
                    int o = nj * 16 + l15;
                    MSG[el][o] = (acc[mi][nj][r] + bs2[nj]) * XT[(long)rn * 32 + o];
                }
            }
        }
    }
    __syncthreads();
    const int colv = tid & 31, g = tid >> 5;
    const int nr = nruns;
    for (int ri = g; ri < nr; ri += 8) {
        int cc = runc[ri];
        if (cc < 0) continue;
        int a = runst[ri], b = runst[ri + 1];
        float s = 0.f;
        for (int e = a; e < b; ++e) s += MSG[e][colv];
        float* dst = AGG + (long)cc * 32 + colv;
        if (a > 0 && b < 256) *dst = s;
        else atomicAdd(dst, s);
    }
}

// ---------------------------------------------------------------------------
// Node GEMM N=256: Y = X(M,K)@Wh(256,K)^T + bias.
// ---------------------------------------------------------------------------
template <int K>
__global__ __launch_bounds__(256) void node_mfma(
    const float* __restrict__ X, const unsigned short* __restrict__ Wh,
    const float* __restrict__ bias, float* __restrict__ Y, int M) {
    __shared__ __align__(16) unsigned short As[4][64][8];
    __shared__ __align__(16) unsigned short Bs[4][256][8];
    const int tid = threadIdx.x;
    const int wv = tid >> 6, lane = tid & 63;
    const int l15 = lane & 15, l4 = lane >> 4;
    const long m0 = (long)blockIdx.x * 64;
    f32x4 acc[4][4] = {};

    const int sr = tid >> 2, sg = tid & 3;
    const long arow = m0 + sr;
    const float* aptr = X + arow * K + sg * 8;
    const bool aok = arow < M;
    const unsigned short* bptr = Wh + (long)tid * K;

    for (int it = 0; it < K / 32; ++it) {
        const int k0 = it * 32;
        u16x8 ap = {};
        if (aok) {
            float4 v0 = *(const float4*)(aptr + k0);
            float4 v1 = *(const float4*)(aptr + k0 + 4);
            ap[0] = f2bf(v0.x); ap[1] = f2bf(v0.y); ap[2] = f2bf(v0.z); ap[3] = f2bf(v0.w);
            ap[4] = f2bf(v1.x); ap[5] = f2bf(v1.y); ap[6] = f2bf(v1.z); ap[7] = f2bf(v1.w);
        }
        u16x8 b0 = *(const u16x8*)(bptr + k0);
        u16x8 b1 = *(const u16x8*)(bptr + k0 + 8);
        u16x8 b2 = *(const u16x8*)(bptr + k0 + 16);
        u16x8 b3 = *(const u16x8*)(bptr + k0 + 24);
        __syncthreads();
        *(u16x8*)&As[sg][sr][0] = ap;
        *(u16x8*)&Bs[0][tid][0] = b0;
        *(u16x8*)&Bs[1][tid][0] = b1;
        *(u16x8*)&Bs[2][tid][0] = b2;
        *(u16x8*)&Bs[3][tid][0] = b3;
        __syncthreads();
        bf16x8 af[4], bfv[4];
#pragma unroll
        for (int mi = 0; mi < 4; ++mi)
            af[mi] = *(const bf16x8*)&As[l4][mi * 16 + l15][0];
#pragma unroll
        for (int nj = 0; nj < 4; ++nj)
            bfv[nj] = *(const bf16x8*)&Bs[l4][wv * 64 + nj * 16 + l15][0];
#pragma unroll
        for (int mi = 0; mi < 4; ++mi)
#pragma unroll
            for (int nj = 0; nj < 4; ++nj)
                acc[mi][nj] = __builtin_amdgcn_mfma_f32_16x16x32_bf16(
                    af[mi], bfv[nj], acc[mi][nj], 0, 0, 0);
    }

    const int nb = wv * 64;
    float bs[4];
#pragma unroll
    for (int nj = 0; nj < 4; ++nj) bs[nj] = bias[nb + nj * 16 + l15];
#pragma unroll
    for (int mi = 0; mi < 4; ++mi) {
#pragma unroll
        for (int r = 0; r < 4; ++r) {
            long gm = m0 + mi * 16 + l4 * 4 + r;
            if (gm < M) {
#pragma unroll
                for (int nj = 0; nj < 4; ++nj)
                    Y[gm * 256 + nb + nj * 16 + l15] = acc[mi][nj][r] + bs[nj];
            }
        }
    }
}

// ---------------------------------------------------------------------------
// KAN linear N=256: Y = expand8(AGG)(M,2048) @ Wch(256,2048)^T.
// ---------------------------------------------------------------------------
__global__ __launch_bounds__(256) void kan_mfma256(
    const float* __restrict__ AGG, const unsigned short* __restrict__ Wch,
    float* __restrict__ Y, int M) {
    __shared__ __align__(16) unsigned short As[4][64][8];
    __shared__ __align__(16) unsigned short Bs[4][256][8];
    const int tid = threadIdx.x;
    const int wv = tid >> 6, lane = tid & 63;
    const int l15 = lane & 15, l4 = lane >> 4;
    const long m0 = (long)blockIdx.x * 64;
    f32x4 acc[4][4] = {};

    const int srow = tid & 63, sg = tid >> 6;
    const long arow = m0 + srow;
    const bool aok = arow < M;
    const float* aptr = AGG + arow * 256 + sg;
    const unsigned short* bptr = Wch + (long)tid * 2048;

    for (int it = 0; it < 64; ++it) {
        float xv = aok ? aptr[it * 4] : 0.f;
        float e8[8];
        expand8(xv, e8);
        u16x8 ap;
#pragma unroll
        for (int c = 0; c < 8; ++c) ap[c] = f2bf(e8[c]);
        const int k0 = it * 32;
        u16x8 b0 = *(const u16x8*)(bptr + k0);
        u16x8 b1 = *(const u16x8*)(bptr + k0 + 8);
        u16x8 b2 = *(const u16x8*)(bptr + k0 + 16);
        u16x8 b3 = *(const u16x8*)(bptr + k0 + 24);
        __syncthreads();
        *(u16x8*)&As[sg][srow][0] = ap;
        *(u16x8*)&Bs[0][tid][0] = b0;
        *(u16x8*)&Bs[1][tid][0] = b1;
        *(u16x8*)&Bs[2][tid][0] = b2;
        *(u16x8*)&Bs[3][tid][0] = b3;
        __syncthreads();
        bf16x8 af[4], bfv[4];
#pragma unroll
        for (int mi = 0; mi < 4; ++mi)
            af[mi] = *(const bf16x8*)&As[l4][mi * 16 + l15][0];
#pragma unroll
        for (int nj = 0; nj < 4; ++nj)
            bfv[nj] = *(const bf16x8*)&Bs[l4][wv * 64 + nj * 16 + l15][0];
#pragma unroll
        for (int mi = 0; mi < 4; ++mi)
#pragma unroll
            for (int nj = 0; nj < 4; ++nj)
                acc[mi][nj] = __builtin_amdgcn_mfma_f32_16x16x32_bf16(
                    af[mi], bfv[nj], acc[mi][nj], 0, 0, 0);
    }

    const int nb = wv * 64;
#pragma unroll
    for (int mi = 0; mi < 4; ++mi) {
#pragma unroll
        for (int r = 0; r < 4; ++r) {
            long gm = m0 + mi * 16 + l4 * 4 + r;
            if (gm < M) {
#pragma unroll
                for (int nj = 0; nj < 4; ++nj)
                    Y[gm * 256 + nb + nj * 16 + l15] = acc[mi][nj][r];
            }
        }
    }
}

// ---------------------------------------------------------------------------
// Node GEMM for concat input, N=32: Y = [x|h0|h1](M,768) @ Wh(32,768)^T + b.
// ---------------------------------------------------------------------------
__global__ __launch_bounds__(256) void node_cat_mfma(
    const float* __restrict__ X, const float* __restrict__ H0,
    const float* __restrict__ H1, const unsigned short* __restrict__ Wh,
    const float* __restrict__ bias, float* __restrict__ Y, int M) {
    __shared__ __align__(16) unsigned short As[4][256][8];
    __shared__ __align__(16) unsigned short Bs[4][32][8];
    const int tid = threadIdx.x;
    const int wv = tid >> 6, lane = tid & 63;
    const int l15 = lane & 15, l4 = lane >> 4;
    const long m0 = (long)blockIdx.x * 256;
    f32x4 acc[4][2] = {};

    const int sr = tid >> 3;
    const int sq = (tid & 7) * 4;
    const int sg2 = sq >> 3, so2 = sq & 7;

    for (int it = 0; it < 24; ++it) {
        const int k0 = it * 32;
        const float* src = (it < 8) ? X : (it < 16) ? H0 : H1;
        const int kk = k0 & 255;
        float4 va[8];
#pragma unroll
        for (int j = 0; j < 8; ++j) {
            long r_ = m0 + j * 32 + sr;
            va[j] = (r_ < M) ? *(const float4*)(src + r_ * 256 + kk + sq)
                             : make_float4(0.f, 0.f, 0.f, 0.f);
        }
        u16x8 bv = {};
        if (tid < 128)
            bv = *(const u16x8*)(Wh + (long)(tid >> 2) * 768 + k0 + (tid & 3) * 8);
        __syncthreads();
#pragma unroll
        for (int j = 0; j < 8; ++j) {
            u16x4 ap;
            ap[0] = f2bf(va[j].x); ap[1] = f2bf(va[j].y);
            ap[2] = f2bf(va[j].z); ap[3] = f2bf(va[j].w);
            *(u16x4*)&As[sg2][j * 32 + sr][so2] = ap;
        }
        if (tid < 128) *(u16x8*)&Bs[tid & 3][tid >> 2][0] = bv;
        __syncthreads();
        bf16x8 af[4], bfv[2];
#pragma unroll
        for (int mi = 0; mi < 4; ++mi)
            af[mi] = *(const bf16x8*)&As[l4][wv * 64 + mi * 16 + l15][0];
#pragma unroll
        for (int nj = 0; nj < 2; ++nj)
            bfv[nj] = *(const bf16x8*)&Bs[l4][nj * 16 + l15][0];
#pragma unroll
        for (int mi = 0; mi < 4; ++mi)
#pragma unroll
            for (int nj = 0; nj < 2; ++nj)
                acc[mi][nj] = __builtin_amdgcn_mfma_f32_16x16x32_bf16(
                    af[mi], bfv[nj], acc[mi][nj], 0, 0, 0);
    }

#pragma unroll
    for (int mi = 0; mi < 4; ++mi) {
#pragma unroll
        for (int r = 0; r < 4; ++r) {
            long gm = m0 + wv * 64 + mi * 16 + l4 * 4 + r;
            if (gm < M) {
#pragma unroll
                for (int nj = 0; nj < 2; ++nj) {
                    int o = nj * 16 + l15;
                    Y[gm * 32 + o] = acc[mi][nj][r] + bias[o];
                }
            }
        }
    }
}

// ---------------------------------------------------------------------------
// Small f32 KAN for output layer (M x 32 -> M x 32).
// ---------------------------------------------------------------------------
__global__ __launch_bounds__(256) void kan_gemm32(
    const float* __restrict__ AGG, const float* __restrict__ Wc,
    float* __restrict__ Y, int M) {
    __shared__ float As[64][36];
    __shared__ float Bs[32][36];
    const int tid = threadIdx.x;
    const int tx = tid & 15, ty = tid >> 4;
    const int m0 = blockIdx.x * 64;
    float acc[4][2] = {{0.f, 0.f}, {0.f, 0.f}, {0.f, 0.f}, {0.f, 0.f}};
    const int er = tid >> 2, ef = tid & 3;
    const int em = m0 + er;
    for (int ic = 0; ic < 32; ic += 4) {
        float xv = (em < M) ? AGG[(long)em * 32 + ic + ef] : 0.f;
        float e8[8];
        expand8(xv, e8);
        *(float4*)&As[er][ef * 8] = make_float4(e8[0], e8[1], e8[2], e8[3]);
        *(float4*)&As[er][ef * 8 + 4] = make_float4(e8[4], e8[5], e8[6], e8[7]);
        {
            int o = tid >> 3, k4 = (tid & 7) * 4;
            *(float4*)&Bs[o][k4] = *(const float4*)&Wc[(long)o * 256 + ic * 8 + k4];
        }
        __syncthreads();
#pragma unroll
        for (int kk = 0; kk < 32; ++kk) {
            float a_[4], b_[2];
#pragma unroll
            for (int i = 0; i < 4; ++i) a_[i] = As[ty * 4 + i][kk];
#pragma unroll
            for (int j = 0; j < 2; ++j) b_[j] = Bs[tx * 2 + j][kk];
#pragma unroll
            for (int i = 0; i < 4; ++i)
#pragma unroll
                for (int j = 0; j < 2; ++j) acc[i][j] = fmaf(a_[i], b_[j], acc[i][j]);
        }
        __syncthreads();
    }
#pragma unroll
    for (int i = 0; i < 4; ++i) {
        int gm = m0 + ty * 4 + i;
        if (gm >= M) continue;
#pragma unroll
        for (int j = 0; j < 2; ++j) Y[(long)gm * 32 + tx * 2 + j] = acc[i][j];
    }
}

// ---------------------------------------------------------------------------
// Weight prep
// ---------------------------------------------------------------------------
__global__ __launch_bounds__(256) void cvt_bf16(
    const float* __restrict__ s, unsigned short* __restrict__ d, int n) {
    int i = blockIdx.x * 256 + threadIdx.x;
    if (i < n) d[i] = f2bf(s[i]);
}

__global__ __launch_bounds__(256) void pack_kan_bf16(
    const float* __restrict__ baseW, const float* __restrict__ splineW,
    unsigned short* __restrict__ Wc, int n) {
    int idx = blockIdx.x * 256 + threadIdx.x;
    if (idx >= n) return;
    unsigned short* dst = Wc + (long)idx * 8;
    dst[0] = f2bf(baseW[idx]);
    const float* sw = splineW + (long)idx * 7;
#pragma unroll
    for (int c = 0; c < 7; ++c) dst[1 + c] = f2bf(sw[c]);
}

__global__ __launch_bounds__(256) void pack_kan_f32(
    const float* __restrict__ baseW, const float* __restrict__ splineW,
    float* __restrict__ Wc, int n) {
    int idx = blockIdx.x * 256 + threadIdx.x;
    if (idx >= n) return;
    float* dst = Wc + (long)idx * 8;
    dst[0] = baseW[idx];
    const float* sw = splineW + (long)idx * 7;
#pragma unroll
    for (int c = 0; c < 7; ++c) dst[1 + c] = sw[c];
}

// ---------------------------------------------------------------------------
extern "C" void kernel_launch(void* const* d_in, const int* in_sizes, int n_in,
                              void* d_out, int out_size, void* d_ws, size_t ws_size,
                              hipStream_t stream) {
    const float* x          = (const float*)d_in[0];
    const int*   edge_index = (const int*)d_in[1];
    const float* edge_attr  = (const float*)d_in[2];
    const float* node_W0 = (const float*)d_in[3];
    const float* node_b0 = (const float*)d_in[4];
    const float* edge_W0 = (const float*)d_in[5];
    const float* edge_b0 = (const float*)d_in[6];
    const float* base_W0 = (const float*)d_in[7];
    const float* spline_W0 = (const float*)d_in[8];
    const float* node_W1 = (const float*)d_in[9];
    const float* node_b1 = (const float*)d_in[10];
    const float* edge_W1 = (const float*)d_in[11];
    const float* edge_b1 = (const float*)d_in[12];
    const float* base_W1 = (const float*)d_in[13];
    const float* spline_W1 = (const float*)d_in[14];
    const float* node_Wo = (const float*)d_in[15];
    const float* node_bo = (const float*)d_in[16];
    const float* edge_Wo = (const float*)d_in[17];
    const float* edge_bo = (const float*)d_in[18];
    const float* base_Wo = (const float*)d_in[19];
    const float* spline_Wo = (const float*)d_in[20];
    float* out = (float*)d_out;

    const int N = in_sizes[0] / 256;
    const int E = in_sizes[1] / 2;

    float* ws  = (float*)d_ws;
    float* xt  = ws;                       // N*256 (also (N,32) for out layer)
    float* agg = xt + (long)N * 256;       // N*256
    float* h0  = agg + (long)N * 256;
    float* h1  = h0 + (long)N * 256;
    float* Wco = h1 + (long)N * 256;       // 32*256 f32
    unsigned short* Wc0h = (unsigned short*)(Wco + 32 * 256);
    unsigned short* Wc1h = Wc0h + 256 * 2048;
    unsigned short* eW0h = Wc1h + 256 * 2048;
    unsigned short* eW1h = eW0h + 256 * 384;
    unsigned short* eWoh = eW1h + 256 * 384;
    unsigned short* nW0h = eWoh + 32 * 384;
    unsigned short* nW1h = nW0h + 256 * 256;
    unsigned short* nWoh = nW1h + 256 * 256;   // 32*768
    int* cursor = (int*)(nWoh + 32 * 768);     // N+1
    int* rowS   = cursor + (N + 1);
    int* eidS   = rowS + E;
    int* colS   = eidS + E;
    // pre-tiled sorted bf16 EA, 256-aligned
    unsigned short* EAs = (unsigned short*)(((uintptr_t)(colS + E) + 255) & ~(uintptr_t)255);

    const int nt256 = (E + 255) / 256;
    const long Epad = (long)nt256 * 256;       // multiple of 256 (and 64)
    const size_t need = (size_t)((char*)EAs - (char*)d_ws) + (size_t)Epad * 384 * 2;
    const bool pre = ws_size >= need;

    const int* row = edge_index;
    const int* col = edge_index + E;

    const int nb64 = (N + 63) / 64;
    const int eb64 = (E + 63) / 64;
    const int eb256 = (E + 255) / 256;
    const int nb256 = (N + 255) / 256;

    // ---- counting sort of edges by destination ----
    hipMemsetAsync(cursor, 0, (size_t)(N + 1) * sizeof(int), stream);
    k_hist<<<eb256, 256, 0, stream>>>(col, cursor, E);
    k_scan<<<1, 1024, 0, stream>>>(cursor, N);
    k_scatter<<<eb256, 256, 0, stream>>>(row, col, cursor, rowS, eidS, colS, E);

    // ---- gather EA into sorted pre-tiled bf16 (reused by all 3 layers) ----
    if (pre)
        gather_ea<<<(int)(Epad * 64 / 256), 256, 0, stream>>>(
            edge_attr, eidS, EAs, E, (int)Epad);

    // ---- weight prep ----
    cvt_bf16<<<(256 * 384 + 255) / 256, 256, 0, stream>>>(edge_W0, eW0h, 256 * 384);
    cvt_bf16<<<(256 * 384 + 255) / 256, 256, 0, stream>>>(edge_W1, eW1h, 256 * 384);
    cvt_bf16<<<(32 * 384 + 255) / 256, 256, 0, stream>>>(edge_Wo, eWoh, 32 * 384);
    cvt_bf16<<<(256 * 256 + 255) / 256, 256, 0, stream>>>(node_W0, nW0h, 256 * 256);
    cvt_bf16<<<(256 * 256 + 255) / 256, 256, 0, stream>>>(node_W1, nW1h, 256 * 256);
    cvt_bf16<<<(32 * 768 + 255) / 256, 256, 0, stream>>>(node_Wo, nWoh, 32 * 768);
    pack_kan_bf16<<<(256 * 256 + 255) / 256, 256, 0, stream>>>(base_W0, spline_W0, Wc0h, 256 * 256);
    pack_kan_bf16<<<(256 * 256 + 255) / 256, 256, 0, stream>>>(base_W1, spline_W1, Wc1h, 256 * 256);
    pack_kan_f32<<<(32 * 32 + 255) / 256, 256, 0, stream>>>(base_Wo, spline_Wo, Wco, 32 * 32);

    // ---- layer 0 ----
    hipMemsetAsync(agg, 0, (size_t)N * 256 * sizeof(float), stream);
    node_mfma<256><<<nb64, 256, 0, stream>>>(x, nW0h, node_b0, xt, N);
    if (pre)
        edge_mfma256_p<<<eb64, 256, 0, stream>>>(EAs, eW0h, edge_b0, xt, rowS, colS, agg, E);
    else
        edge_mfma256_s<<<eb64, 256, 0, stream>>>(edge_attr, eW0h, edge_b0, xt, rowS, colS, eidS, agg, E);
    kan_mfma256<<<nb64, 256, 0, stream>>>(agg, Wc0h, h0, N);

    // ---- layer 1 ----
    hipMemsetAsync(agg, 0, (size_t)N * 256 * sizeof(float), stream);
    node_mfma<256><<<nb64, 256, 0, stream>>>(h0, nW1h, node_b1, xt, N);
    if (pre)
        edge_mfma256_p<<<eb64, 256, 0, stream>>>(EAs, eW1h, edge_b1, xt, rowS, colS, agg, E);
    else
        edge_mfma256_s<<<eb64, 256, 0, stream>>>(edge_attr, eW1h, edge_b1, xt, rowS, colS, eidS, agg, E);
    kan_mfma256<<<nb64, 256, 0, stream>>>(agg, Wc1h, h1, N);

    // ---- output layer ----
    hipMemsetAsync(agg, 0, (size_t)N * 32 * sizeof(float), stream);
    node_cat_mfma<<<nb256, 256, 0, stream>>>(x, h0, h1, nWoh, node_bo, xt, N);
    if (pre)
        edge_mfma32_p<<<eb256, 256, 0, stream>>>(EAs, eWoh, edge_bo, xt, rowS, colS, agg, E);
    else
        edge_mfma32_s<<<eb256, 256, 0, stream>>>(edge_attr, eWoh, edge_bo, xt, rowS, colS, eidS, agg, E);
    kan_gemm32<<<nb64, 256, 0, stream>>>(agg, Wco, out, N);
}

// Round 3
// 2059.594 us; speedup vs baseline: 1.0910x; 1.0910x over previous
//
#include <hip/hip_runtime.h>

// ---------------------------------------------------------------------------
// GCKAN (3 layers) on MI355X — round 5.
// Edge kernels: global_load_lds (16B) + double-buffered LDS, ONE barrier per
// K-step, ballot-parallel run table, rowS cached in LDS, bf16 XT (halves the
// random-scatter bytes; XT=25.6MB ~ L2-resident).
// ---------------------------------------------------------------------------

typedef __attribute__((ext_vector_type(4))) float f32x4;
typedef __attribute__((ext_vector_type(8))) short bf16x8;
typedef __attribute__((ext_vector_type(8))) unsigned short u16x8;
typedef __attribute__((ext_vector_type(4))) unsigned short u16x4;

__device__ __forceinline__ unsigned short f2bf(float f) {
    union { float f; unsigned u; } v; v.f = f;
    unsigned r = v.u + 0x7FFFu + ((v.u >> 16) & 1u);
    return (unsigned short)(r >> 16);
}

__device__ __forceinline__ float bf2f(unsigned short u) {
    union { unsigned u; float f; } v; v.u = ((unsigned)u) << 16;
    return v.f;
}

__device__ __forceinline__ float siluf(float x) {
    return x / (1.0f + __expf(-x));
}

// async global->LDS, 16B per lane; dest = wave-uniform base + lane*16.
__device__ __forceinline__ void gl16(const void* g, void* l) {
    __builtin_amdgcn_global_load_lds(
        (const __attribute__((address_space(1))) unsigned*)g,
        (__attribute__((address_space(3))) unsigned*)l, 16, 0, 0);
}

// Expand scalar x -> 8 channels [silu, B0..B6]; cubic B-spline on uniform
// knots t_i = 0.5 i - 2.5 (matches reference Cox-de Boor exactly).
__device__ __forceinline__ void expand8(float x, float* o8) {
    float b[10];
#pragma unroll
    for (int i = 0; i < 10; ++i) {
        float ti = 0.5f * i - 2.5f;
        b[i] = (x >= ti && x < ti + 0.5f) ? 1.0f : 0.0f;
    }
#pragma unroll
    for (int j = 1; j <= 3; ++j) {
        float inv = 2.0f / (float)j;
#pragma unroll
        for (int i = 0; i < 10 - j; ++i) {
            float ti = 0.5f * i - 2.5f;
            float tj = 0.5f * (i + j + 1) - 2.5f;
            b[i] = (x - ti) * inv * b[i] + (tj - x) * inv * b[i + 1];
        }
    }
    o8[0] = siluf(x);
#pragma unroll
    for (int c = 0; c < 7; ++c) o8[c + 1] = b[c];
}

// ---------------------------------------------------------------------------
// Edge counting sort by destination (col).
// ---------------------------------------------------------------------------
__global__ __launch_bounds__(256) void k_hist(
    const int* __restrict__ col, int* __restrict__ cnt, int E) {
    int i = blockIdx.x * 256 + threadIdx.x;
    if (i < E) atomicAdd(&cnt[col[i]], 1);
}

__global__ __launch_bounds__(1024) void k_scan(int* __restrict__ c, int N) {
    __shared__ int wsum[16];
    __shared__ int ctot;
    const int t = threadIdx.x;
    const int lane = t & 63, wid = t >> 6;
    int carry = 0;
    for (int base = 0; base < N; base += 1024) {
        int i = base + t;
        int v0 = (i < N) ? c[i] : 0;
        int v = v0;
#pragma unroll
        for (int off = 1; off < 64; off <<= 1) {
            int n = __shfl_up(v, (unsigned)off, 64);
            if (lane >= off) v += n;
        }
        if (lane == 63) wsum[wid] = v;
        __syncthreads();
        if (t < 16) {
            int s = wsum[t], sv = s;
#pragma unroll
            for (int off = 1; off < 16; off <<= 1) {
                int n = __shfl_up(sv, (unsigned)off, 16);
                if (t >= off) sv += n;
            }
            wsum[t] = sv - s;
            if (t == 15) ctot = sv;
        }
        __syncthreads();
        if (i < N) c[i] = carry + wsum[wid] + v - v0;
        carry += ctot;
        __syncthreads();
    }
}

__global__ __launch_bounds__(256) void k_scatter(
    const int* __restrict__ row, const int* __restrict__ col,
    int* __restrict__ cursor, int* __restrict__ rowS,
    int* __restrict__ eidS, int* __restrict__ colS, int E) {
    int i = blockIdx.x * 256 + threadIdx.x;
    if (i < E) {
        int c = col[i];
        int p = atomicAdd(&cursor[c], 1);
        rowS[p] = row[i];
        eidS[p] = i;
        colS[p] = c;
    }
}

// ---------------------------------------------------------------------------
// Gather EA rows into sorted order, bf16, pre-tiled:
// tile t (64 edges) = 24576 u16; within: [it][g][r][c] for k = it*32+g*8+c.
// Full-lane version: one 16B output (from 32B f32 input) per thread.
// ---------------------------------------------------------------------------
__global__ __launch_bounds__(256) void gather_ea(
    const float* __restrict__ EA, const int* __restrict__ eidS,
    unsigned short* __restrict__ EAs, int E, long total) {
    long idx = (long)blockIdx.x * 256 + threadIdx.x;   // = p*48 + l
    if (idx >= total) return;
    long p = idx / 48;
    int l = (int)(idx - p * 48);
    u16x8 o = {};
    if (p < E) {
        const float* src = EA + (long)eidS[p] * 384 + l * 8;
        float4 v0 = *(const float4*)src;
        float4 v1 = *(const float4*)(src + 4);
        o[0] = f2bf(v0.x); o[1] = f2bf(v0.y); o[2] = f2bf(v0.z); o[3] = f2bf(v0.w);
        o[4] = f2bf(v1.x); o[5] = f2bf(v1.y); o[6] = f2bf(v1.z); o[7] = f2bf(v1.w);
    }
    long t = p >> 6;
    int r = (int)(p & 63);
    int it = l >> 2, g = l & 3;
    *(u16x8*)(EAs + t * 24576 + it * 2048 + g * 512 + r * 8) = o;
}

// ---------------------------------------------------------------------------
// Fused edge layer N=256: 64 sorted edges x 256 outs, 4 waves.
// global_load_lds + double-buffered LDS, one barrier per K-step.
// ---------------------------------------------------------------------------
__global__ __launch_bounds__(256) void edge_mfma256_p2(
    const unsigned short* __restrict__ EAs, const unsigned short* __restrict__ Wh,
    const float* __restrict__ eb, const unsigned short* __restrict__ XT,
    const int* __restrict__ rowS, const int* __restrict__ colS,
    float* __restrict__ AGG, int E) {
    __shared__ __align__(16) char smem[40960];   // A2 2x4K | B2 2x16K ; MSG union
    unsigned short (*A2)[4][64][8]  = (unsigned short (*)[4][64][8])smem;
    unsigned short (*B2)[4][256][8] = (unsigned short (*)[4][256][8])(smem + 8192);
    float (*MSG)[130] = (float (*)[130])smem;    // 33280 B, used after K loop
    __shared__ int cols_s[64];
    __shared__ int rows_s[64];
    __shared__ int runst[65];
    __shared__ int runc[64];
    __shared__ int nruns;

    const int tid = threadIdx.x;
    const int wv = tid >> 6, lane = tid & 63;
    const int l15 = lane & 15, l4 = lane >> 4;
    const long m0 = (long)blockIdx.x * 64;
    f32x4 acc[4][4] = {};

    const char* srcA = (const char*)(EAs + (long)blockIdx.x * 24576);
    const unsigned short* bptr = Wh + (long)tid * 384;

    // ---- run table, ballot-parallel (wave 0) ----
    if (tid < 64) {
        long p = m0 + tid;
        cols_s[tid] = (p < E) ? colS[p] : -1;
        rows_s[tid] = (p < E) ? rowS[p] : 0;
    }
    __syncthreads();
    if (tid < 64) {
        int cc = cols_s[tid];
        bool flag = (tid == 0) || (cc != cols_s[tid - 1]);
        unsigned long long m = __ballot(flag);
        if (flag) {
            int idx = __popcll(m & ((1ull << tid) - 1ull));
            runst[idx] = tid; runc[idx] = cc;
        }
        if (tid == 0) {
            int nr = __popcll(m);
            nruns = nr; runst[nr] = 64;
        }
    }

    // ---- staging helper: 5 global_load_lds per thread per K-step ----
#define STAGE256(IT, BUF)                                                      \
    {                                                                          \
        gl16(srcA + ((long)(IT) * 256 + tid) * 16,                             \
             smem + (BUF) * 4096 + wv * 1024);                                 \
        _Pragma("unroll")                                                      \
        for (int g = 0; g < 4; ++g)                                            \
            gl16(bptr + (IT) * 32 + g * 8,                                     \
                 smem + 8192 + (BUF) * 16384 + g * 4096 + wv * 1024);          \
    }

    STAGE256(0, 0);
    for (int it = 0; it < 12; ++it) {
        const int buf = it & 1;
        __syncthreads();                  // implicit vmcnt(0): buf ready
        if (it < 11) STAGE256(it + 1, buf ^ 1);
        bf16x8 af[4], bfv[4];
#pragma unroll
        for (int mi = 0; mi < 4; ++mi)
            af[mi] = *(const bf16x8*)&A2[buf][l4][mi * 16 + l15][0];
#pragma unroll
        for (int nj = 0; nj < 4; ++nj)
            bfv[nj] = *(const bf16x8*)&B2[buf][l4][wv * 64 + nj * 16 + l15][0];
#pragma unroll
        for (int mi = 0; mi < 4; ++mi)
#pragma unroll
            for (int nj = 0; nj < 4; ++nj)
                acc[mi][nj] = __builtin_amdgcn_mfma_f32_16x16x32_bf16(
                    af[mi], bfv[nj], acc[mi][nj], 0, 0, 0);
    }
#undef STAGE256

    const int nb = wv * 64;
    float bs[4];
#pragma unroll
    for (int nj = 0; nj < 4; ++nj) bs[nj] = eb[nb + nj * 16 + l15];

#pragma unroll
    for (int p = 0; p < 2; ++p) {
        __syncthreads();
        if ((wv >> 1) == p) {
            const int cb = nb - p * 128;
#pragma unroll
            for (int mi = 0; mi < 4; ++mi) {
#pragma unroll
                for (int r = 0; r < 4; ++r) {
                    int el = mi * 16 + l4 * 4 + r;
                    long e = m0 + el;
                    if (e < E) {
                        int rn = rows_s[el];
                        const unsigned short* xr = XT + (long)rn * 256 + nb + l15;
                        float* mrow = &MSG[el][cb + l15];
#pragma unroll
                        for (int nj = 0; nj < 4; ++nj)
                            mrow[nj * 16] =
                                (acc[mi][nj][r] + bs[nj]) * bf2f(xr[nj * 16]);
                    }
                }
            }
        }
        __syncthreads();
        const int colv = tid & 127, g = tid >> 7;
        const int nr = nruns;
        for (int ri = g; ri < nr; ri += 2) {
            int cc = runc[ri];
            if (cc < 0) continue;
            int a = runst[ri], b = runst[ri + 1];
            float s = 0.f;
            for (int e = a; e < b; ++e) s += MSG[e][colv];
            float* dst = AGG + (long)cc * 256 + p * 128 + colv;
            if (a > 0 && b < 64) *dst = s;
            else atomicAdd(dst, s);
        }
    }
}

// ---------------------------------------------------------------------------
// Fused edge layer N=32 (output layer): 256 sorted edges x 32 outs.
// ---------------------------------------------------------------------------
__global__ __launch_bounds__(256) void edge_mfma32_p2(
    const unsigned short* __restrict__ EAs, const unsigned short* __restrict__ Wh,
    const float* __restrict__ eb, const unsigned short* __restrict__ XT,
    const int* __restrict__ rowS, const int* __restrict__ colS,
    float* __restrict__ AGG, int E) {
    __shared__ __align__(16) char smem[36864];   // A2 2x16K | B2 2x1K ; MSG union
    unsigned short (*A2)[4][4][64][8] = (unsigned short (*)[4][4][64][8])smem;
    unsigned short (*B2)[4][32][8]    = (unsigned short (*)[4][32][8])(smem + 32768);
    float (*MSG)[34] = (float (*)[34])smem;      // 34816 B
    __shared__ int cols_s[256];
    __shared__ int rows_s[256];
    __shared__ int runst[257];
    __shared__ int runc[256];
    __shared__ int wcnt[4];
    __shared__ int nruns;

    const int tid = threadIdx.x;
    const int wv = tid >> 6, lane = tid & 63;
    const int l15 = lane & 15, l4 = lane >> 4;
    const long m0 = (long)blockIdx.x * 256;
    const long t0 = (long)blockIdx.x * 4;
    f32x4 acc[4][2] = {};

    const char* eabase = (const char*)EAs;

    // ---- run table, ballot-parallel (4 waves) ----
    {
        long p = m0 + tid;
        cols_s[tid] = (p < E) ? colS[p] : -1;
        rows_s[tid] = (p < E) ? rowS[p] : 0;
    }
    __syncthreads();
    {
        int cc = cols_s[tid];
        bool flag = (tid == 0) || (cc != cols_s[tid - 1]);
        unsigned long long m = __ballot(flag);
        if (lane == 63) wcnt[wv] = __popcll(m);
        __syncthreads();
        int base = 0;
        for (int w = 0; w < wv; ++w) base += wcnt[w];
        if (flag) {
            int idx = base + __popcll(m & ((1ull << lane) - 1ull));
            runst[idx] = tid; runc[idx] = cc;
        }
        if (tid == 255) {
            int nr = base + __popcll(m);
            nruns = nr; runst[nr] = 256;
        }
    }

#define STAGE32(IT, BUF)                                                       \
    {                                                                          \
        _Pragma("unroll")                                                      \
        for (int q = 0; q < 4; ++q)                                            \
            gl16(eabase + (t0 + q) * 49152 + (long)(IT) * 4096 + tid * 16,     \
                 smem + (BUF) * 16384 + q * 4096 + wv * 1024);                 \
        if (tid < 128) {                                                       \
            int gg = wv * 2 + (lane >> 5);                                     \
            int oo = lane & 31;                                                \
            gl16(Wh + (long)oo * 384 + (IT) * 32 + gg * 8,                     \
                 smem + 32768 + (BUF) * 2048 + wv * 1024);                     \
        }                                                                      \
    }

    STAGE32(0, 0);
    for (int it = 0; it < 12; ++it) {
        const int buf = it & 1;
        __syncthreads();
        if (it < 11) STAGE32(it + 1, buf ^ 1);
        bf16x8 af[4], bfv[2];
#pragma unroll
        for (int mi = 0; mi < 4; ++mi)
            af[mi] = *(const bf16x8*)&A2[buf][wv][l4][mi * 16 + l15][0];
#pragma unroll
        for (int nj = 0; nj < 2; ++nj)
            bfv[nj] = *(const bf16x8*)&B2[buf][l4][nj * 16 + l15][0];
#pragma unroll
        for (int mi = 0; mi < 4; ++mi)
#pragma unroll
            for (int nj = 0; nj < 2; ++nj)
                acc[mi][nj] = __builtin_amdgcn_mfma_f32_16x16x32_bf16(
                    af[mi], bfv[nj], acc[mi][nj], 0, 0, 0);
    }
#undef STAGE32

    float bs2[2];
#pragma unroll
    for (int nj = 0; nj < 2; ++nj) bs2[nj] = eb[nj * 16 + l15];

    __syncthreads();   // staging reads done; reuse smem as MSG
#pragma unroll
    for (int mi = 0; mi < 4; ++mi) {
#pragma unroll
        for (int r = 0; r < 4; ++r) {
            int el = wv * 64 + mi * 16 + l4 * 4 + r;
            long e = m0 + el;
            if (e < E) {
                int rn = rows_s[el];
#pragma unroll
                for (int nj = 0; nj < 2; ++nj) {
                    int o = nj * 16 + l15;
                    MSG[el][o] = (acc[mi][nj][r] + bs2[nj]) * bf2f(XT[(long)rn * 32 + o]);
                }
            }
        }
    }
    __syncthreads();
    const int colv = tid & 31, g = tid >> 5;
    const int nr = nruns;
    for (int ri = g; ri < nr; ri += 8) {
        int cc = runc[ri];
        if (cc < 0) continue;
        int a = runst[ri], b = runst[ri + 1];
        float s = 0.f;
        for (int e = a; e < b; ++e) s += MSG[e][colv];
        float* dst = AGG + (long)cc * 32 + colv;
        if (a > 0 && b < 256) *dst = s;
        else atomicAdd(dst, s);
    }
}

// ---------------------------------------------------------------------------
// Node GEMM N=256: Y(bf16) = X(M,K)@Wh(256,K)^T + bias.
// ---------------------------------------------------------------------------
template <int K>
__global__ __launch_bounds__(256) void node_mfma(
    const float* __restrict__ X, const unsigned short* __restrict__ Wh,
    const float* __restrict__ bias, unsigned short* __restrict__ Y, int M) {
    __shared__ __align__(16) unsigned short As[4][64][8];
    __shared__ __align__(16) unsigned short Bs[4][256][8];
    const int tid = threadIdx.x;
    const int wv = tid >> 6, lane = tid & 63;
    const int l15 = lane & 15, l4 = lane >> 4;
    const long m0 = (long)blockIdx.x * 64;
    f32x4 acc[4][4] = {};

    const int sr = tid >> 2, sg = tid & 3;
    const long arow = m0 + sr;
    const float* aptr = X + arow * K + sg * 8;
    const bool aok = arow < M;
    const unsigned short* bptr = Wh + (long)tid * K;

    for (int it = 0; it < K / 32; ++it) {
        const int k0 = it * 32;
        u16x8 ap = {};
        if (aok) {
            float4 v0 = *(const float4*)(aptr + k0);
            float4 v1 = *(const float4*)(aptr + k0 + 4);
            ap[0] = f2bf(v0.x); ap[1] = f2bf(v0.y); ap[2] = f2bf(v0.z); ap[3] = f2bf(v0.w);
            ap[4] = f2bf(v1.x); ap[5] = f2bf(v1.y); ap[6] = f2bf(v1.z); ap[7] = f2bf(v1.w);
        }
        u16x8 b0 = *(const u16x8*)(bptr + k0);
        u16x8 b1 = *(const u16x8*)(bptr + k0 + 8);
        u16x8 b2 = *(const u16x8*)(bptr + k0 + 16);
        u16x8 b3 = *(const u16x8*)(bptr + k0 + 24);
        __syncthreads();
        *(u16x8*)&As[sg][sr][0] = ap;
        *(u16x8*)&Bs[0][tid][0] = b0;
        *(u16x8*)&Bs[1][tid][0] = b1;
        *(u16x8*)&Bs[2][tid][0] = b2;
        *(u16x8*)&Bs[3][tid][0] = b3;
        __syncthreads();
        bf16x8 af[4], bfv[4];
#pragma unroll
        for (int mi = 0; mi < 4; ++mi)
            af[mi] = *(const bf16x8*)&As[l4][mi * 16 + l15][0];
#pragma unroll
        for (int nj = 0; nj < 4; ++nj)
            bfv[nj] = *(const bf16x8*)&Bs[l4][wv * 64 + nj * 16 + l15][0];
#pragma unroll
        for (int mi = 0; mi < 4; ++mi)
#pragma unroll
            for (int nj = 0; nj < 4; ++nj)
                acc[mi][nj] = __builtin_amdgcn_mfma_f32_16x16x32_bf16(
                    af[mi], bfv[nj], acc[mi][nj], 0, 0, 0);
    }

    const int nb = wv * 64;
    float bs[4];
#pragma unroll
    for (int nj = 0; nj < 4; ++nj) bs[nj] = bias[nb + nj * 16 + l15];
#pragma unroll
    for (int mi = 0; mi < 4; ++mi) {
#pragma unroll
        for (int r = 0; r < 4; ++r) {
            long gm = m0 + mi * 16 + l4 * 4 + r;
            if (gm < M) {
#pragma unroll
                for (int nj = 0; nj < 4; ++nj)
                    Y[gm * 256 + nb + nj * 16 + l15] = f2bf(acc[mi][nj][r] + bs[nj]);
            }
        }
    }
}

// ---------------------------------------------------------------------------
// KAN linear N=256: Y = expand8(AGG)(M,2048) @ Wch(256,2048)^T. B-prefetch.
// ---------------------------------------------------------------------------
__global__ __launch_bounds__(256) void kan_mfma256(
    const float* __restrict__ AGG, const unsigned short* __restrict__ Wch,
    float* __restrict__ Y, int M) {
    __shared__ __align__(16) unsigned short As[4][64][8];
    __shared__ __align__(16) unsigned short Bs[4][256][8];
    const int tid = threadIdx.x;
    const int wv = tid >> 6, lane = tid & 63;
    const int l15 = lane & 15, l4 = lane >> 4;
    const long m0 = (long)blockIdx.x * 64;
    f32x4 acc[4][4] = {};

    const int srow = tid & 63, sg = tid >> 6;
    const long arow = m0 + srow;
    const bool aok = arow < M;
    const float* aptr = AGG + arow * 256 + sg;
    const unsigned short* bptr = Wch + (long)tid * 2048;

    float xv = aok ? aptr[0] : 0.f;
    u16x8 pb0 = *(const u16x8*)(bptr);
    u16x8 pb1 = *(const u16x8*)(bptr + 8);
    u16x8 pb2 = *(const u16x8*)(bptr + 16);
    u16x8 pb3 = *(const u16x8*)(bptr + 24);

    for (int it = 0; it < 64; ++it) {
        float e8[8];
        expand8(xv, e8);
        u16x8 ap;
#pragma unroll
        for (int c = 0; c < 8; ++c) ap[c] = f2bf(e8[c]);
        __syncthreads();
        *(u16x8*)&As[sg][srow][0] = ap;
        *(u16x8*)&Bs[0][tid][0] = pb0;
        *(u16x8*)&Bs[1][tid][0] = pb1;
        *(u16x8*)&Bs[2][tid][0] = pb2;
        *(u16x8*)&Bs[3][tid][0] = pb3;
        __syncthreads();
        if (it < 63) {
            xv = aok ? aptr[(it + 1) * 4] : 0.f;
            const int k0 = (it + 1) * 32;
            pb0 = *(const u16x8*)(bptr + k0);
            pb1 = *(const u16x8*)(bptr + k0 + 8);
            pb2 = *(const u16x8*)(bptr + k0 + 16);
            pb3 = *(const u16x8*)(bptr + k0 + 24);
        }
        bf16x8 af[4], bfv[4];
#pragma unroll
        for (int mi = 0; mi < 4; ++mi)
            af[mi] = *(const bf16x8*)&As[l4][mi * 16 + l15][0];
#pragma unroll
        for (int nj = 0; nj < 4; ++nj)
            bfv[nj] = *(const bf16x8*)&Bs[l4][wv * 64 + nj * 16 + l15][0];
#pragma unroll
        for (int mi = 0; mi < 4; ++mi)
#pragma unroll
            for (int nj = 0; nj < 4; ++nj)
                acc[mi][nj] = __builtin_amdgcn_mfma_f32_16x16x32_bf16(
                    af[mi], bfv[nj], acc[mi][nj], 0, 0, 0);
    }

    const int nb = wv * 64;
#pragma unroll
    for (int mi = 0; mi < 4; ++mi) {
#pragma unroll
        for (int r = 0; r < 4; ++r) {
            long gm = m0 + mi * 16 + l4 * 4 + r;
            if (gm < M) {
#pragma unroll
                for (int nj = 0; nj < 4; ++nj)
                    Y[gm * 256 + nb + nj * 16 + l15] = acc[mi][nj][r];
            }
        }
    }
}

// ---------------------------------------------------------------------------
// Node GEMM for concat input, N=32: Y(bf16) = [x|h0|h1](M,768)@Wh(32,768)^T+b.
// ---------------------------------------------------------------------------
__global__ __launch_bounds__(256) void node_cat_mfma(
    const float* __restrict__ X, const float* __restrict__ H0,
    const float* __restrict__ H1, const unsigned short* __restrict__ Wh,
    const float* __restrict__ bias, unsigned short* __restrict__ Y, int M) {
    __shared__ __align__(16) unsigned short As[4][256][8];
    __shared__ __align__(16) unsigned short Bs[4][32][8];
    const int tid = threadIdx.x;
    const int wv = tid >> 6, lane = tid & 63;
    const int l15 = lane & 15, l4 = lane >> 4;
    const long m0 = (long)blockIdx.x * 256;
    f32x4 acc[4][2] = {};

    const int sr = tid >> 3;
    const int sq = (tid & 7) * 4;
    const int sg2 = sq >> 3, so2 = sq & 7;

    for (int it = 0; it < 24; ++it) {
        const int k0 = it * 32;
        const float* src = (it < 8) ? X : (it < 16) ? H0 : H1;
        const int kk = k0 & 255;
        float4 va[8];
#pragma unroll
        for (int j = 0; j < 8; ++j) {
            long r_ = m0 + j * 32 + sr;
            va[j] = (r_ < M) ? *(const float4*)(src + r_ * 256 + kk + sq)
                             : make_float4(0.f, 0.f, 0.f, 0.f);
        }
        u16x8 bv = {};
        if (tid < 128)
            bv = *(const u16x8*)(Wh + (long)(tid >> 2) * 768 + k0 + (tid & 3) * 8);
        __syncthreads();
#pragma unroll
        for (int j = 0; j < 8; ++j) {
            u16x4 ap;
            ap[0] = f2bf(va[j].x); ap[1] = f2bf(va[j].y);
            ap[2] = f2bf(va[j].z); ap[3] = f2bf(va[j].w);
            *(u16x4*)&As[sg2][j * 32 + sr][so2] = ap;
        }
        if (tid < 128) *(u16x8*)&Bs[tid & 3][tid >> 2][0] = bv;
        __syncthreads();
        bf16x8 af[4], bfv[2];
#pragma unroll
        for (int mi = 0; mi < 4; ++mi)
            af[mi] = *(const bf16x8*)&As[l4][wv * 64 + mi * 16 + l15][0];
#pragma unroll
        for (int nj = 0; nj < 2; ++nj)
            bfv[nj] = *(const bf16x8*)&Bs[l4][nj * 16 + l15][0];
#pragma unroll
        for (int mi = 0; mi < 4; ++mi)
#pragma unroll
            for (int nj = 0; nj < 2; ++nj)
                acc[mi][nj] = __builtin_amdgcn_mfma_f32_16x16x32_bf16(
                    af[mi], bfv[nj], acc[mi][nj], 0, 0, 0);
    }

#pragma unroll
    for (int mi = 0; mi < 4; ++mi) {
#pragma unroll
        for (int r = 0; r < 4; ++r) {
            long gm = m0 + wv * 64 + mi * 16 + l4 * 4 + r;
            if (gm < M) {
#pragma unroll
                for (int nj = 0; nj < 2; ++nj) {
                    int o = nj * 16 + l15;
                    Y[gm * 32 + o] = f2bf(acc[mi][nj][r] + bias[o]);
                }
            }
        }
    }
}

// ---------------------------------------------------------------------------
// Small f32 KAN for output layer (M x 32 -> M x 32).
// ---------------------------------------------------------------------------
__global__ __launch_bounds__(256) void kan_gemm32(
    const float* __restrict__ AGG, const float* __restrict__ Wc,
    float* __restrict__ Y, int M) {
    __shared__ float As[64][36];
    __shared__ float Bs[32][36];
    const int tid = threadIdx.x;
    const int tx = tid & 15, ty = tid >> 4;
    const int m0 = blockIdx.x * 64;
    float acc[4][2] = {{0.f, 0.f}, {0.f, 0.f}, {0.f, 0.f}, {0.f, 0.f}};
    const int er = tid >> 2, ef = tid & 3;
    const int em = m0 + er;
    for (int ic = 0; ic < 32; ic += 4) {
        float xv = (em < M) ? AGG[(long)em * 32 + ic + ef] : 0.f;
        float e8[8];
        expand8(xv, e8);
        *(float4*)&As[er][ef * 8] = make_float4(e8[0], e8[1], e8[2], e8[3]);
        *(float4*)&As[er][ef * 8 + 4] = make_float4(e8[4], e8[5], e8[6], e8[7]);
        {
            int o = tid >> 3, k4 = (tid & 7) * 4;
            *(float4*)&Bs[o][k4] = *(const float4*)&Wc[(long)o * 256 + ic * 8 + k4];
        }
        __syncthreads();
#pragma unroll
        for (int kk = 0; kk < 32; ++kk) {
            float a_[4], b_[2];
#pragma unroll
            for (int i = 0; i < 4; ++i) a_[i] = As[ty * 4 + i][kk];
#pragma unroll
            for (int j = 0; j < 2; ++j) b_[j] = Bs[tx * 2 + j][kk];
#pragma unroll
            for (int i = 0; i < 4; ++i)
#pragma unroll
                for (int j = 0; j < 2; ++j) acc[i][j] = fmaf(a_[i], b_[j], acc[i][j]);
        }
        __syncthreads();
    }
#pragma unroll
    for (int i = 0; i < 4; ++i) {
        int gm = m0 + ty * 4 + i;
        if (gm >= M) continue;
#pragma unroll
        for (int j = 0; j < 2; ++j) Y[(long)gm * 32 + tx * 2 + j] = acc[i][j];
    }
}

// ---------------------------------------------------------------------------
// Weight prep
// ---------------------------------------------------------------------------
__global__ __launch_bounds__(256) void cvt_bf16(
    const float* __restrict__ s, unsigned short* __restrict__ d, int n) {
    int i = blockIdx.x * 256 + threadIdx.x;
    if (i < n) d[i] = f2bf(s[i]);
}

__global__ __launch_bounds__(256) void pack_kan_bf16(
    const float* __restrict__ baseW, const float* __restrict__ splineW,
    unsigned short* __restrict__ Wc, int n) {
    int idx = blockIdx.x * 256 + threadIdx.x;
    if (idx >= n) return;
    unsigned short* dst = Wc + (long)idx * 8;
    dst[0] = f2bf(baseW[idx]);
    const float* sw = splineW + (long)idx * 7;
#pragma unroll
    for (int c = 0; c < 7; ++c) dst[1 + c] = f2bf(sw[c]);
}

__global__ __launch_bounds__(256) void pack_kan_f32(
    const float* __restrict__ baseW, const float* __restrict__ splineW,
    float* __restrict__ Wc, int n) {
    int idx = blockIdx.x * 256 + threadIdx.x;
    if (idx >= n) return;
    float* dst = Wc + (long)idx * 8;
    dst[0] = baseW[idx];
    const float* sw = splineW + (long)idx * 7;
#pragma unroll
    for (int c = 0; c < 7; ++c) dst[1 + c] = sw[c];
}

// ---------------------------------------------------------------------------
extern "C" void kernel_launch(void* const* d_in, const int* in_sizes, int n_in,
                              void* d_out, int out_size, void* d_ws, size_t ws_size,
                              hipStream_t stream) {
    const float* x          = (const float*)d_in[0];
    const int*   edge_index = (const int*)d_in[1];
    const float* edge_attr  = (const float*)d_in[2];
    const float* node_W0 = (const float*)d_in[3];
    const float* node_b0 = (const float*)d_in[4];
    const float* edge_W0 = (const float*)d_in[5];
    const float* edge_b0 = (const float*)d_in[6];
    const float* base_W0 = (const float*)d_in[7];
    const float* spline_W0 = (const float*)d_in[8];
    const float* node_W1 = (const float*)d_in[9];
    const float* node_b1 = (const float*)d_in[10];
    const float* edge_W1 = (const float*)d_in[11];
    const float* edge_b1 = (const float*)d_in[12];
    const float* base_W1 = (const float*)d_in[13];
    const float* spline_W1 = (const float*)d_in[14];
    const float* node_Wo = (const float*)d_in[15];
    const float* node_bo = (const float*)d_in[16];
    const float* edge_Wo = (const float*)d_in[17];
    const float* edge_bo = (const float*)d_in[18];
    const float* base_Wo = (const float*)d_in[19];
    const float* spline_Wo = (const float*)d_in[20];
    float* out = (float*)d_out;

    const int N = in_sizes[0] / 256;
    const int E = in_sizes[1] / 2;

    float* ws  = (float*)d_ws;
    unsigned short* xt = (unsigned short*)ws;  // bf16 XT, slot sized N*256 f32
    float* agg = ws + (long)N * 256;           // N*256 f32
    float* h0  = agg + (long)N * 256;
    float* h1  = h0 + (long)N * 256;
    float* Wco = h1 + (long)N * 256;           // 32*256 f32
    unsigned short* Wc0h = (unsigned short*)(Wco + 32 * 256);
    unsigned short* Wc1h = Wc0h + 256 * 2048;
    unsigned short* eW0h = Wc1h + 256 * 2048;
    unsigned short* eW1h = eW0h + 256 * 384;
    unsigned short* eWoh = eW1h + 256 * 384;
    unsigned short* nW0h = eWoh + 32 * 384;
    unsigned short* nW1h = nW0h + 256 * 256;
    unsigned short* nWoh = nW1h + 256 * 256;   // 32*768
    int* cursor = (int*)(nWoh + 32 * 768);     // N+1
    int* rowS   = cursor + (N + 1);
    int* eidS   = rowS + E;
    int* colS   = eidS + E;
    unsigned short* EAs = (unsigned short*)(((uintptr_t)(colS + E) + 255) & ~(uintptr_t)255);

    const int nt256 = (E + 255) / 256;
    const long Epad = (long)nt256 * 256;       // multiple of 256 (and 64)

    const int* row = edge_index;
    const int* col = edge_index + E;

    const int nb64 = (N + 63) / 64;
    const int eb64 = (E + 63) / 64;
    const int eb256 = (E + 255) / 256;
    const int nb256 = (N + 255) / 256;

    // ---- counting sort of edges by destination ----
    hipMemsetAsync(cursor, 0, (size_t)(N + 1) * sizeof(int), stream);
    k_hist<<<eb256, 256, 0, stream>>>(col, cursor, E);
    k_scan<<<1, 1024, 0, stream>>>(cursor, N);
    k_scatter<<<eb256, 256, 0, stream>>>(row, col, cursor, rowS, eidS, colS, E);

    // ---- gather EA into sorted pre-tiled bf16 (reused by all 3 layers) ----
    {
        long total = Epad * 48;
        gather_ea<<<(int)((total + 255) / 256), 256, 0, stream>>>(
            edge_attr, eidS, EAs, E, total);
    }

    // ---- weight prep ----
    cvt_bf16<<<(256 * 384 + 255) / 256, 256, 0, stream>>>(edge_W0, eW0h, 256 * 384);
    cvt_bf16<<<(256 * 384 + 255) / 256, 256, 0, stream>>>(edge_W1, eW1h, 256 * 384);
    cvt_bf16<<<(32 * 384 + 255) / 256, 256, 0, stream>>>(edge_Wo, eWoh, 32 * 384);
    cvt_bf16<<<(256 * 256 + 255) / 256, 256, 0, stream>>>(node_W0, nW0h, 256 * 256);
    cvt_bf16<<<(256 * 256 + 255) / 256, 256, 0, stream>>>(node_W1, nW1h, 256 * 256);
    cvt_bf16<<<(32 * 768 + 255) / 256, 256, 0, stream>>>(node_Wo, nWoh, 32 * 768);
    pack_kan_bf16<<<(256 * 256 + 255) / 256, 256, 0, stream>>>(base_W0, spline_W0, Wc0h, 256 * 256);
    pack_kan_bf16<<<(256 * 256 + 255) / 256, 256, 0, stream>>>(base_W1, spline_W1, Wc1h, 256 * 256);
    pack_kan_f32<<<(32 * 32 + 255) / 256, 256, 0, stream>>>(base_Wo, spline_Wo, Wco, 32 * 32);

    // ---- layer 0 ----
    hipMemsetAsync(agg, 0, (size_t)N * 256 * sizeof(float), stream);
    node_mfma<256><<<nb64, 256, 0, stream>>>(x, nW0h, node_b0, xt, N);
    edge_mfma256_p2<<<eb64, 256, 0, stream>>>(EAs, eW0h, edge_b0, xt, rowS, colS, agg, E);
    kan_mfma256<<<nb64, 256, 0, stream>>>(agg, Wc0h, h0, N);

    // ---- layer 1 ----
    hipMemsetAsync(agg, 0, (size_t)N * 256 * sizeof(float), stream);
    node_mfma<256><<<nb64, 256, 0, stream>>>(h0, nW1h, node_b1, xt, N);
    edge_mfma256_p2<<<eb64, 256, 0, stream>>>(EAs, eW1h, edge_b1, xt, rowS, colS, agg, E);
    kan_mfma256<<<nb64, 256, 0, stream>>>(agg, Wc1h, h1, N);

    // ---- output layer ----
    hipMemsetAsync(agg, 0, (size_t)N * 32 * sizeof(float), stream);
    node_cat_mfma<<<nb256, 256, 0, stream>>>(x, h0, h1, nWoh, node_bo, xt, N);
    edge_mfma32_p2<<<eb256, 256, 0, stream>>>(EAs, eWoh, edge_bo, xt, rowS, colS, agg, E);
    kan_gemm32<<<nb64, 256, 0, stream>>>(agg, Wco, out, N);
}

// Round 4
// 1813.837 us; speedup vs baseline: 1.2388x; 1.1355x over previous
//
#include <hip/hip_runtime.h>

// ---------------------------------------------------------------------------
// GCKAN (3 layers) on MI355X — round 6: split edge layer into
//   (a) pure dense GEMM ea = EA@W^T + b  (original-order read, sorted write)
//   (b) streaming message/reduce kernel (register run-accumulation)
// The fused kernel was pinned at ~530us with nothing busy (3 coupled phases
// serializing at 3 blocks/CU). Gather pass deleted (reads EA directly).
// ---------------------------------------------------------------------------

typedef __attribute__((ext_vector_type(4))) float f32x4;
typedef __attribute__((ext_vector_type(8))) short bf16x8;
typedef __attribute__((ext_vector_type(8))) unsigned short u16x8;
typedef __attribute__((ext_vector_type(4))) unsigned short u16x4;

__device__ __forceinline__ unsigned short f2bf(float f) {
    union { float f; unsigned u; } v; v.f = f;
    unsigned r = v.u + 0x7FFFu + ((v.u >> 16) & 1u);
    return (unsigned short)(r >> 16);
}

__device__ __forceinline__ float bf2f(unsigned short u) {
    union { unsigned u; float f; } v; v.u = ((unsigned)u) << 16;
    return v.f;
}

__device__ __forceinline__ float siluf(float x) {
    return x / (1.0f + __expf(-x));
}

// async global->LDS, 16B per lane; dest must be WAVE-UNIFORM (HW adds lane*16).
__device__ __forceinline__ void gl16(const void* g, void* l) {
    __builtin_amdgcn_global_load_lds(
        (const __attribute__((address_space(1))) unsigned*)g,
        (__attribute__((address_space(3))) unsigned*)l, 16, 0, 0);
}

// Expand scalar x -> 8 channels [silu, B0..B6]; cubic B-spline on uniform
// knots t_i = 0.5 i - 2.5 (matches reference Cox-de Boor exactly).
__device__ __forceinline__ void expand8(float x, float* o8) {
    float b[10];
#pragma unroll
    for (int i = 0; i < 10; ++i) {
        float ti = 0.5f * i - 2.5f;
        b[i] = (x >= ti && x < ti + 0.5f) ? 1.0f : 0.0f;
    }
#pragma unroll
    for (int j = 1; j <= 3; ++j) {
        float inv = 2.0f / (float)j;
#pragma unroll
        for (int i = 0; i < 10 - j; ++i) {
            float ti = 0.5f * i - 2.5f;
            float tj = 0.5f * (i + j + 1) - 2.5f;
            b[i] = (x - ti) * inv * b[i] + (tj - x) * inv * b[i + 1];
        }
    }
    o8[0] = siluf(x);
#pragma unroll
    for (int c = 0; c < 7; ++c) o8[c + 1] = b[c];
}

// ---------------------------------------------------------------------------
// Edge counting sort by destination (col). posS[i] = sorted position of edge i.
// ---------------------------------------------------------------------------
__global__ __launch_bounds__(256) void k_hist(
    const int* __restrict__ col, int* __restrict__ cnt, int E) {
    int i = blockIdx.x * 256 + threadIdx.x;
    if (i < E) atomicAdd(&cnt[col[i]], 1);
}

__global__ __launch_bounds__(1024) void k_scan(int* __restrict__ c, int N) {
    __shared__ int wsum[16];
    __shared__ int ctot;
    const int t = threadIdx.x;
    const int lane = t & 63, wid = t >> 6;
    int carry = 0;
    for (int base = 0; base < N; base += 1024) {
        int i = base + t;
        int v0 = (i < N) ? c[i] : 0;
        int v = v0;
#pragma unroll
        for (int off = 1; off < 64; off <<= 1) {
            int n = __shfl_up(v, (unsigned)off, 64);
            if (lane >= off) v += n;
        }
        if (lane == 63) wsum[wid] = v;
        __syncthreads();
        if (t < 16) {
            int s = wsum[t], sv = s;
#pragma unroll
            for (int off = 1; off < 16; off <<= 1) {
                int n = __shfl_up(sv, (unsigned)off, 16);
                if (t >= off) sv += n;
            }
            wsum[t] = sv - s;
            if (t == 15) ctot = sv;
        }
        __syncthreads();
        if (i < N) c[i] = carry + wsum[wid] + v - v0;
        carry += ctot;
        __syncthreads();
    }
}

__global__ __launch_bounds__(256) void k_scatter(
    const int* __restrict__ row, const int* __restrict__ col,
    int* __restrict__ cursor, int* __restrict__ rowS,
    int* __restrict__ colS, int* __restrict__ posS, int E) {
    int i = blockIdx.x * 256 + threadIdx.x;
    if (i < E) {
        int c = col[i];
        int p = atomicAdd(&cursor[c], 1);
        rowS[p] = row[i];
        colS[p] = c;
        posS[i] = p;
    }
}

// ---------------------------------------------------------------------------
// Dense edge GEMM: ea = EA(E,384)@Wh(256,384)^T + eb, bf16 rows stored at
// SORTED positions. Optionally also Wo(32,384) -> EAro. Tile 64 edges x 256.
// A reg-staged (f32->bf16), B via global_load_lds, dbuf, 1 barrier/K-step.
// ---------------------------------------------------------------------------
template <bool WITH_O>
__global__ __launch_bounds__(256) void ea_gemm(
    const float* __restrict__ EA, const unsigned short* __restrict__ Wh,
    const float* __restrict__ eb, const unsigned short* __restrict__ Woh,
    const float* __restrict__ ebo, const int* __restrict__ posS,
    unsigned short* __restrict__ EAr, unsigned short* __restrict__ EAro, int E) {
    // A2: 2 x [4][64][8]u16 @0 (8KB); B2: 2 x [4][256][8]u16 @8192 (32KB);
    // Bo2 (WITH_O): 2 x [4][32][8]u16 @40960 (4KB)
    __shared__ __align__(16) char smem[WITH_O ? 45056 : 40960];
    __shared__ int pos_s[64];
    const int tid = threadIdx.x;
    const int wv = tid >> 6, lane = tid & 63;
    const int l15 = lane & 15, l4 = lane >> 4;
    const long m0 = (long)blockIdx.x * 64;
    f32x4 acc[4][4] = {};
    f32x4 acco[4] = {};

    const int sr = tid >> 2, sg = tid & 3;
    const long arow = m0 + sr;
    const bool aok = arow < E;
    const float* aptr = EA + arow * 384 + sg * 8;
    const unsigned short* bptr = Wh + (long)tid * 384;   // per-lane B source
    const unsigned short* boptr = Woh;
    if (WITH_O) {
        int o = wv * 1024 + lane * 16;        // flat byte within 2KB Bo buf
        int g = o >> 9, brow = (o >> 4) & 31;
        boptr = Woh + (long)brow * 384 + g * 8;
    }
    if (tid < 64) { long p = m0 + tid; pos_s[tid] = (p < E) ? posS[p] : -1; }

    u16x8* const awp0 = (u16x8*)(smem + sg * 1024 + sr * 16);
    u16x8* const awp1 = (u16x8*)(smem + 4096 + sg * 1024 + sr * 16);

    // prologue: A(0) to LDS buf0, B(0)/Bo(0) gl16 buf0, A(1) in regs
    u16x8 areg;
    {
        u16x8 r = {};
        if (aok) {
            float4 v0 = *(const float4*)(aptr);
            float4 v1 = *(const float4*)(aptr + 4);
            r[0] = f2bf(v0.x); r[1] = f2bf(v0.y); r[2] = f2bf(v0.z); r[3] = f2bf(v0.w);
            r[4] = f2bf(v1.x); r[5] = f2bf(v1.y); r[6] = f2bf(v1.z); r[7] = f2bf(v1.w);
        }
        *awp0 = r;
    }
#pragma unroll
    for (int g = 0; g < 4; ++g)
        gl16(bptr + g * 8, smem + 8192 + g * 4096 + wv * 1024);
    if (WITH_O && wv < 2)
        gl16(boptr, smem + 40960 + wv * 1024);
    {
        u16x8 r = {};
        if (aok) {
            float4 v0 = *(const float4*)(aptr + 32);
            float4 v1 = *(const float4*)(aptr + 36);
            r[0] = f2bf(v0.x); r[1] = f2bf(v0.y); r[2] = f2bf(v0.z); r[3] = f2bf(v0.w);
            r[4] = f2bf(v1.x); r[5] = f2bf(v1.y); r[6] = f2bf(v1.z); r[7] = f2bf(v1.w);
        }
        areg = r;
    }

    for (int it = 0; it < 12; ++it) {
        const int buf = it & 1;
        __syncthreads();      // buf staged (barrier drains vmcnt+lgkmcnt)
        if (it < 11) {
            const int nbf = buf ^ 1;
#pragma unroll
            for (int g = 0; g < 4; ++g)
                gl16(bptr + (it + 1) * 32 + g * 8,
                     smem + 8192 + nbf * 16384 + g * 4096 + wv * 1024);
            if (WITH_O && wv < 2)
                gl16(boptr + (it + 1) * 32, smem + 40960 + nbf * 2048 + wv * 1024);
            *(nbf ? awp1 : awp0) = areg;
            if (it < 10) {
                u16x8 r = {};
                if (aok) {
                    const float* p = aptr + (it + 2) * 32;
                    float4 v0 = *(const float4*)p;
                    float4 v1 = *(const float4*)(p + 4);
                    r[0] = f2bf(v0.x); r[1] = f2bf(v0.y); r[2] = f2bf(v0.z); r[3] = f2bf(v0.w);
                    r[4] = f2bf(v1.x); r[5] = f2bf(v1.y); r[6] = f2bf(v1.z); r[7] = f2bf(v1.w);
                }
                areg = r;
            }
        }
        bf16x8 af[4], bfv[4];
#pragma unroll
        for (int mi = 0; mi < 4; ++mi)
            af[mi] = *(const bf16x8*)(smem + buf * 4096 + l4 * 1024 + (mi * 16 + l15) * 16);
#pragma unroll
        for (int nj = 0; nj < 4; ++nj)
            bfv[nj] = *(const bf16x8*)(smem + 8192 + buf * 16384 + l4 * 4096 +
                                       (wv * 64 + nj * 16 + l15) * 16);
#pragma unroll
        for (int mi = 0; mi < 4; ++mi)
#pragma unroll
            for (int nj = 0; nj < 4; ++nj)
                acc[mi][nj] = __builtin_amdgcn_mfma_f32_16x16x32_bf16(
                    af[mi], bfv[nj], acc[mi][nj], 0, 0, 0);
        if (WITH_O && wv < 2) {
            bf16x8 bo = *(const bf16x8*)(smem + 40960 + buf * 2048 + l4 * 512 +
                                         (wv * 16 + l15) * 16);
#pragma unroll
            for (int mi = 0; mi < 4; ++mi)
                acco[mi] = __builtin_amdgcn_mfma_f32_16x16x32_bf16(
                    af[mi], bo, acco[mi], 0, 0, 0);
        }
    }

    const int nb2 = wv * 64;
    float bs[4];
#pragma unroll
    for (int nj = 0; nj < 4; ++nj) bs[nj] = eb[nb2 + nj * 16 + l15];
#pragma unroll
    for (int mi = 0; mi < 4; ++mi) {
#pragma unroll
        for (int r = 0; r < 4; ++r) {
            int edge = mi * 16 + l4 * 4 + r;
            int pos = pos_s[edge];
            if (pos >= 0) {
                unsigned short* dst = EAr + (long)pos * 256 + nb2 + l15;
#pragma unroll
                for (int nj = 0; nj < 4; ++nj)
                    dst[nj * 16] = f2bf(acc[mi][nj][r] + bs[nj]);
            }
        }
    }
    if (WITH_O && wv < 2) {
        float bso = ebo[wv * 16 + l15];
#pragma unroll
        for (int mi = 0; mi < 4; ++mi) {
#pragma unroll
            for (int r = 0; r < 4; ++r) {
                int edge = mi * 16 + l4 * 4 + r;
                int pos = pos_s[edge];
                if (pos >= 0)
                    EAro[(long)pos * 32 + wv * 16 + l15] = f2bf(acco[mi][r] + bso);
            }
        }
    }
}

// ---------------------------------------------------------------------------
// Message+reduce, N=256: per 64-sorted-edge tile, thread owns one column,
// accumulates runs of equal dest in registers; plain store for interior runs.
// ---------------------------------------------------------------------------
__global__ __launch_bounds__(256) void msg256(
    const unsigned short* __restrict__ EAr, const unsigned short* __restrict__ XT,
    const int* __restrict__ rowS, const int* __restrict__ colS,
    float* __restrict__ AGG, int E) {
    __shared__ __align__(16) unsigned short eas[64][256];   // 32KB
    __shared__ int rows_s[64];
    __shared__ int cols_s[64];
    const int tid = threadIdx.x;
    const int wv = tid >> 6, lane = tid & 63;
    const long m0 = (long)blockIdx.x * 64;

    const char* src = (const char*)(EAr + m0 * 256);
#pragma unroll
    for (int j = 0; j < 8; ++j)
        gl16(src + (j * 4 + wv) * 1024 + lane * 16,
             ((char*)&eas[0][0]) + (j * 4 + wv) * 1024);
    if (tid < 64) {
        long p = m0 + tid;
        cols_s[tid] = (p < E) ? colS[p] : -1;
        rows_s[tid] = (p < E) ? rowS[p] : 0;
    }
    __syncthreads();

    const int c = tid;            // 0..255
    float sum = 0.f;
    int cur = cols_s[0];
    int runstart = 0;
#pragma unroll 1
    for (int g = 0; g < 8; ++g) {
        float xv[8];
#pragma unroll
        for (int j = 0; j < 8; ++j)
            xv[j] = bf2f(XT[(long)rows_s[g * 8 + j] * 256 + c]);
#pragma unroll
        for (int j = 0; j < 8; ++j) {
            int e = g * 8 + j;
            int cc = cols_s[e];
            if (cc != cur) {                 // uniform branch (cols_s broadcast)
                if (cur >= 0) {
                    float* dst = AGG + (long)cur * 256 + c;
                    if (runstart > 0) *dst = sum;     // run complete in-tile
                    else atomicAdd(dst, sum);         // may continue prev tile
                }
                cur = cc; runstart = e; sum = 0.f;
            }
            sum += bf2f(eas[e][c]) * xv[j];
        }
    }
    if (cur >= 0) {                          // touches tile end -> atomic
        atomicAdd(AGG + (long)cur * 256 + c, sum);
    }
}

// ---------------------------------------------------------------------------
// Message+reduce, N=32 (output layer): 256-edge tile, thread = (sub, col).
// ---------------------------------------------------------------------------
__global__ __launch_bounds__(256) void msg32(
    const unsigned short* __restrict__ EAro, const unsigned short* __restrict__ XT,
    const int* __restrict__ rowS, const int* __restrict__ colS,
    float* __restrict__ AGG, int E) {
    __shared__ __align__(16) unsigned short eas[256][32];   // 16KB
    __shared__ int rows_s[256];
    __shared__ int cols_s[256];
    const int tid = threadIdx.x;
    const int wv = tid >> 6, lane = tid & 63;
    const long m0 = (long)blockIdx.x * 256;

    const char* src = (const char*)(EAro + m0 * 32);
#pragma unroll
    for (int j = 0; j < 4; ++j)
        gl16(src + (j * 4 + wv) * 1024 + lane * 16,
             ((char*)&eas[0][0]) + (j * 4 + wv) * 1024);
    {
        long p = m0 + tid;
        cols_s[tid] = (p < E) ? colS[p] : -1;
        rows_s[tid] = (p < E) ? rowS[p] : 0;
    }
    __syncthreads();

    const int c = tid & 31, s = tid >> 5;    // 8 sub-tiles of 32 edges
    const int e0 = s * 32;
    float sum = 0.f;
    int cur = cols_s[e0];
    int runstart = e0;
#pragma unroll 1
    for (int g = 0; g < 4; ++g) {
        float xv[8];
#pragma unroll
        for (int j = 0; j < 8; ++j)
            xv[j] = bf2f(XT[(long)rows_s[e0 + g * 8 + j] * 32 + c]);
#pragma unroll
        for (int j = 0; j < 8; ++j) {
            int e = e0 + g * 8 + j;
            int cc = cols_s[e];
            if (cc != cur) {
                if (cur >= 0) {
                    float* dst = AGG + (long)cur * 32 + c;
                    if (runstart > 0 && cols_s[runstart - 1] != cur) *dst = sum;
                    else atomicAdd(dst, sum);
                }
                cur = cc; runstart = e; sum = 0.f;
            }
            sum += bf2f(eas[e][c]) * xv[j];
        }
    }
    if (cur >= 0) {
        int eend = e0 + 32;
        float* dst = AGG + (long)cur * 32 + c;
        bool oks = (runstart > 0 && cols_s[runstart - 1] != cur);
        bool oke = (eend < 256 && cols_s[eend] != cur);
        if (oks && oke) *dst = sum;
        else atomicAdd(dst, sum);
    }
}

// ---------------------------------------------------------------------------
// Node GEMM N=256: Y(bf16) = X(M,K)@Wh(256,K)^T + bias.
// ---------------------------------------------------------------------------
template <int K>
__global__ __launch_bounds__(256) void node_mfma(
    const float* __restrict__ X, const unsigned short* __restrict__ Wh,
    const float* __restrict__ bias, unsigned short* __restrict__ Y, int M) {
    __shared__ __align__(16) unsigned short As[4][64][8];
    __shared__ __align__(16) unsigned short Bs[4][256][8];
    const int tid = threadIdx.x;
    const int wv = tid >> 6, lane = tid & 63;
    const int l15 = lane & 15, l4 = lane >> 4;
    const long m0 = (long)blockIdx.x * 64;
    f32x4 acc[4][4] = {};

    const int sr = tid >> 2, sg = tid & 3;
    const long arow = m0 + sr;
    const float* aptr = X + arow * K + sg * 8;
    const bool aok = arow < M;
    const unsigned short* bptr = Wh + (long)tid * K;

    for (int it = 0; it < K / 32; ++it) {
        const int k0 = it * 32;
        u16x8 ap = {};
        if (aok) {
            float4 v0 = *(const float4*)(aptr + k0);
            float4 v1 = *(const float4*)(aptr + k0 + 4);
            ap[0] = f2bf(v0.x); ap[1] = f2bf(v0.y); ap[2] = f2bf(v0.z); ap[3] = f2bf(v0.w);
            ap[4] = f2bf(v1.x); ap[5] = f2bf(v1.y); ap[6] = f2bf(v1.z); ap[7] = f2bf(v1.w);
        }
        u16x8 b0 = *(const u16x8*)(bptr + k0);
        u16x8 b1 = *(const u16x8*)(bptr + k0 + 8);
        u16x8 b2 = *(const u16x8*)(bptr + k0 + 16);
        u16x8 b3 = *(const u16x8*)(bptr + k0 + 24);
        __syncthreads();
        *(u16x8*)&As[sg][sr][0] = ap;
        *(u16x8*)&Bs[0][tid][0] = b0;
        *(u16x8*)&Bs[1][tid][0] = b1;
        *(u16x8*)&Bs[2][tid][0] = b2;
        *(u16x8*)&Bs[3][tid][0] = b3;
        __syncthreads();
        bf16x8 af[4], bfv[4];
#pragma unroll
        for (int mi = 0; mi < 4; ++mi)
            af[mi] = *(const bf16x8*)&As[l4][mi * 16 + l15][0];
#pragma unroll
        for (int nj = 0; nj < 4; ++nj)
            bfv[nj] = *(const bf16x8*)&Bs[l4][wv * 64 + nj * 16 + l15][0];
#pragma unroll
        for (int mi = 0; mi < 4; ++mi)
#pragma unroll
            for (int nj = 0; nj < 4; ++nj)
                acc[mi][nj] = __builtin_amdgcn_mfma_f32_16x16x32_bf16(
                    af[mi], bfv[nj], acc[mi][nj], 0, 0, 0);
    }

    const int nb = wv * 64;
    float bs[4];
#pragma unroll
    for (int nj = 0; nj < 4; ++nj) bs[nj] = bias[nb + nj * 16 + l15];
#pragma unroll
    for (int mi = 0; mi < 4; ++mi) {
#pragma unroll
        for (int r = 0; r < 4; ++r) {
            long gm = m0 + mi * 16 + l4 * 4 + r;
            if (gm < M) {
#pragma unroll
                for (int nj = 0; nj < 4; ++nj)
                    Y[gm * 256 + nb + nj * 16 + l15] = f2bf(acc[mi][nj][r] + bs[nj]);
            }
        }
    }
}

// ---------------------------------------------------------------------------
// KAN linear N=256: Y = expand8(AGG)(M,2048) @ Wch(256,2048)^T. B-prefetch.
// ---------------------------------------------------------------------------
__global__ __launch_bounds__(256) void kan_mfma256(
    const float* __restrict__ AGG, const unsigned short* __restrict__ Wch,
    float* __restrict__ Y, int M) {
    __shared__ __align__(16) unsigned short As[4][64][8];
    __shared__ __align__(16) unsigned short Bs[4][256][8];
    const int tid = threadIdx.x;
    const int wv = tid >> 6, lane = tid & 63;
    const int l15 = lane & 15, l4 = lane >> 4;
    const long m0 = (long)blockIdx.x * 64;
    f32x4 acc[4][4] = {};

    const int srow = tid & 63, sg = tid >> 6;
    const long arow = m0 + srow;
    const bool aok = arow < M;
    const float* aptr = AGG + arow * 256 + sg;
    const unsigned short* bptr = Wch + (long)tid * 2048;

    float xv = aok ? aptr[0] : 0.f;
    u16x8 pb0 = *(const u16x8*)(bptr);
    u16x8 pb1 = *(const u16x8*)(bptr + 8);
    u16x8 pb2 = *(const u16x8*)(bptr + 16);
    u16x8 pb3 = *(const u16x8*)(bptr + 24);

    for (int it = 0; it < 64; ++it) {
        float e8[8];
        expand8(xv, e8);
        u16x8 ap;
#pragma unroll
        for (int c = 0; c < 8; ++c) ap[c] = f2bf(e8[c]);
        __syncthreads();
        *(u16x8*)&As[sg][srow][0] = ap;
        *(u16x8*)&Bs[0][tid][0] = pb0;
        *(u16x8*)&Bs[1][tid][0] = pb1;
        *(u16x8*)&Bs[2][tid][0] = pb2;
        *(u16x8*)&Bs[3][tid][0] = pb3;
        __syncthreads();
        if (it < 63) {
            xv = aok ? aptr[(it + 1) * 4] : 0.f;
            const int k0 = (it + 1) * 32;
            pb0 = *(const u16x8*)(bptr + k0);
            pb1 = *(const u16x8*)(bptr + k0 + 8);
            pb2 = *(const u16x8*)(bptr + k0 + 16);
            pb3 = *(const u16x8*)(bptr + k0 + 24);
        }
        bf16x8 af[4], bfv[4];
#pragma unroll
        for (int mi = 0; mi < 4; ++mi)
            af[mi] = *(const bf16x8*)&As[l4][mi * 16 + l15][0];
#pragma unroll
        for (int nj = 0; nj < 4; ++nj)
            bfv[nj] = *(const bf16x8*)&Bs[l4][wv * 64 + nj * 16 + l15][0];
#pragma unroll
        for (int mi = 0; mi < 4; ++mi)
#pragma unroll
            for (int nj = 0; nj < 4; ++nj)
                acc[mi][nj] = __builtin_amdgcn_mfma_f32_16x16x32_bf16(
                    af[mi], bfv[nj], acc[mi][nj], 0, 0, 0);
    }

    const int nb = wv * 64;
#pragma unroll
    for (int mi = 0; mi < 4; ++mi) {
#pragma unroll
        for (int r = 0; r < 4; ++r) {
            long gm = m0 + mi * 16 + l4 * 4 + r;
            if (gm < M) {
#pragma unroll
                for (int nj = 0; nj < 4; ++nj)
                    Y[gm * 256 + nb + nj * 16 + l15] = acc[mi][nj][r];
            }
        }
    }
}

// ---------------------------------------------------------------------------
// Node GEMM for concat input, N=32: Y(bf16) = [x|h0|h1](M,768)@Wh(32,768)^T+b.
// ---------------------------------------------------------------------------
__global__ __launch_bounds__(256) void node_cat_mfma(
    const float* __restrict__ X, const float* __restrict__ H0,
    const float* __restrict__ H1, const unsigned short* __restrict__ Wh,
    const float* __restrict__ bias, unsigned short* __restrict__ Y, int M) {
    __shared__ __align__(16) unsigned short As[4][256][8];
    __shared__ __align__(16) unsigned short Bs[4][32][8];
    const int tid = threadIdx.x;
    const int wv = tid >> 6, lane = tid & 63;
    const int l15 = lane & 15, l4 = lane >> 4;
    const long m0 = (long)blockIdx.x * 256;
    f32x4 acc[4][2] = {};

    const int sr = tid >> 3;
    const int sq = (tid & 7) * 4;
    const int sg2 = sq >> 3, so2 = sq & 7;

    for (int it = 0; it < 24; ++it) {
        const int k0 = it * 32;
        const float* src = (it < 8) ? X : (it < 16) ? H0 : H1;
        const int kk = k0 & 255;
        float4 va[8];
#pragma unroll
        for (int j = 0; j < 8; ++j) {
            long r_ = m0 + j * 32 + sr;
            va[j] = (r_ < M) ? *(const float4*)(src + r_ * 256 + kk + sq)
                             : make_float4(0.f, 0.f, 0.f, 0.f);
        }
        u16x8 bv = {};
        if (tid < 128)
            bv = *(const u16x8*)(Wh + (long)(tid >> 2) * 768 + k0 + (tid & 3) * 8);
        __syncthreads();
#pragma unroll
        for (int j = 0; j < 8; ++j) {
            u16x4 ap;
            ap[0] = f2bf(va[j].x); ap[1] = f2bf(va[j].y);
            ap[2] = f2bf(va[j].z); ap[3] = f2bf(va[j].w);
            *(u16x4*)&As[sg2][j * 32 + sr][so2] = ap;
        }
        if (tid < 128) *(u16x8*)&Bs[tid & 3][tid >> 2][0] = bv;
        __syncthreads();
        bf16x8 af[4], bfv[2];
#pragma unroll
        for (int mi = 0; mi < 4; ++mi)
            af[mi] = *(const bf16x8*)&As[l4][wv * 64 + mi * 16 + l15][0];
#pragma unroll
        for (int nj = 0; nj < 2; ++nj)
            bfv[nj] = *(const bf16x8*)&Bs[l4][nj * 16 + l15][0];
#pragma unroll
        for (int mi = 0; mi < 4; ++mi)
#pragma unroll
            for (int nj = 0; nj < 2; ++nj)
                acc[mi][nj] = __builtin_amdgcn_mfma_f32_16x16x32_bf16(
                    af[mi], bfv[nj], acc[mi][nj], 0, 0, 0);
    }

#pragma unroll
    for (int mi = 0; mi < 4; ++mi) {
#pragma unroll
        for (int r = 0; r < 4; ++r) {
            long gm = m0 + wv * 64 + mi * 16 + l4 * 4 + r;
            if (gm < M) {
#pragma unroll
                for (int nj = 0; nj < 2; ++nj) {
                    int o = nj * 16 + l15;
                    Y[gm * 32 + o] = f2bf(acc[mi][nj][r] + bias[o]);
                }
            }
        }
    }
}

// ---------------------------------------------------------------------------
// Small f32 KAN for output layer (M x 32 -> M x 32).
// ---------------------------------------------------------------------------
__global__ __launch_bounds__(256) void kan_gemm32(
    const float* __restrict__ AGG, const float* __restrict__ Wc,
    float* __restrict__ Y, int M) {
    __shared__ float As[64][36];
    __shared__ float Bs[32][36];
    const int tid = threadIdx.x;
    const int tx = tid & 15, ty = tid >> 4;
    const int m0 = blockIdx.x * 64;
    float acc[4][2] = {{0.f, 0.f}, {0.f, 0.f}, {0.f, 0.f}, {0.f, 0.f}};
    const int er = tid >> 2, ef = tid & 3;
    const int em = m0 + er;
    for (int ic = 0; ic < 32; ic += 4) {
        float xv = (em < M) ? AGG[(long)em * 32 + ic + ef] : 0.f;
        float e8[8];
        expand8(xv, e8);
        *(float4*)&As[er][ef * 8] = make_float4(e8[0], e8[1], e8[2], e8[3]);
        *(float4*)&As[er][ef * 8 + 4] = make_float4(e8[4], e8[5], e8[6], e8[7]);
        {
            int o = tid >> 3, k4 = (tid & 7) * 4;
            *(float4*)&Bs[o][k4] = *(const float4*)&Wc[(long)o * 256 + ic * 8 + k4];
        }
        __syncthreads();
#pragma unroll
        for (int kk = 0; kk < 32; ++kk) {
            float a_[4], b_[2];
#pragma unroll
            for (int i = 0; i < 4; ++i) a_[i] = As[ty * 4 + i][kk];
#pragma unroll
            for (int j = 0; j < 2; ++j) b_[j] = Bs[tx * 2 + j][kk];
#pragma unroll
            for (int i = 0; i < 4; ++i)
#pragma unroll
                for (int j = 0; j < 2; ++j) acc[i][j] = fmaf(a_[i], b_[j], acc[i][j]);
        }
        __syncthreads();
    }
#pragma unroll
    for (int i = 0; i < 4; ++i) {
        int gm = m0 + ty * 4 + i;
        if (gm >= M) continue;
#pragma unroll
        for (int j = 0; j < 2; ++j) Y[(long)gm * 32 + tx * 2 + j] = acc[i][j];
    }
}

// ---------------------------------------------------------------------------
// Weight prep
// ---------------------------------------------------------------------------
__global__ __launch_bounds__(256) void cvt_bf16(
    const float* __restrict__ s, unsigned short* __restrict__ d, int n) {
    int i = blockIdx.x * 256 + threadIdx.x;
    if (i < n) d[i] = f2bf(s[i]);
}

__global__ __launch_bounds__(256) void pack_kan_bf16(
    const float* __restrict__ baseW, const float* __restrict__ splineW,
    unsigned short* __restrict__ Wc, int n) {
    int idx = blockIdx.x * 256 + threadIdx.x;
    if (idx >= n) return;
    unsigned short* dst = Wc + (long)idx * 8;
    dst[0] = f2bf(baseW[idx]);
    const float* sw = splineW + (long)idx * 7;
#pragma unroll
    for (int c = 0; c < 7; ++c) dst[1 + c] = f2bf(sw[c]);
}

__global__ __launch_bounds__(256) void pack_kan_f32(
    const float* __restrict__ baseW, const float* __restrict__ splineW,
    float* __restrict__ Wc, int n) {
    int idx = blockIdx.x * 256 + threadIdx.x;
    if (idx >= n) return;
    float* dst = Wc + (long)idx * 8;
    dst[0] = baseW[idx];
    const float* sw = splineW + (long)idx * 7;
#pragma unroll
    for (int c = 0; c < 7; ++c) dst[1 + c] = sw[c];
}

// ---------------------------------------------------------------------------
extern "C" void kernel_launch(void* const* d_in, const int* in_sizes, int n_in,
                              void* d_out, int out_size, void* d_ws, size_t ws_size,
                              hipStream_t stream) {
    const float* x          = (const float*)d_in[0];
    const int*   edge_index = (const int*)d_in[1];
    const float* edge_attr  = (const float*)d_in[2];
    const float* node_W0 = (const float*)d_in[3];
    const float* node_b0 = (const float*)d_in[4];
    const float* edge_W0 = (const float*)d_in[5];
    const float* edge_b0 = (const float*)d_in[6];
    const float* base_W0 = (const float*)d_in[7];
    const float* spline_W0 = (const float*)d_in[8];
    const float* node_W1 = (const float*)d_in[9];
    const float* node_b1 = (const float*)d_in[10];
    const float* edge_W1 = (const float*)d_in[11];
    const float* edge_b1 = (const float*)d_in[12];
    const float* base_W1 = (const float*)d_in[13];
    const float* spline_W1 = (const float*)d_in[14];
    const float* node_Wo = (const float*)d_in[15];
    const float* node_bo = (const float*)d_in[16];
    const float* edge_Wo = (const float*)d_in[17];
    const float* edge_bo = (const float*)d_in[18];
    const float* base_Wo = (const float*)d_in[19];
    const float* spline_Wo = (const float*)d_in[20];
    float* out = (float*)d_out;

    const int N = in_sizes[0] / 256;
    const int E = in_sizes[1] / 2;

    float* ws  = (float*)d_ws;
    unsigned short* xt = (unsigned short*)ws;  // bf16 XT (slot sized N*256 f32)
    float* agg = ws + (long)N * 256;           // N*256 f32
    float* h0  = agg + (long)N * 256;
    float* h1  = h0 + (long)N * 256;
    float* Wco = h1 + (long)N * 256;           // 32*256 f32
    unsigned short* Wc0h = (unsigned short*)(Wco + 32 * 256);
    unsigned short* Wc1h = Wc0h + 256 * 2048;
    unsigned short* eW0h = Wc1h + 256 * 2048;
    unsigned short* eW1h = eW0h + 256 * 384;
    unsigned short* eWoh = eW1h + 256 * 384;
    unsigned short* nW0h = eWoh + 32 * 384;
    unsigned short* nW1h = nW0h + 256 * 256;
    unsigned short* nWoh = nW1h + 256 * 256;   // 32*768
    int* cursor = (int*)(nWoh + 32 * 768);     // N+1
    int* rowS   = cursor + (N + 1);
    int* colS   = rowS + E;
    int* posS   = colS + E;
    // sorted edge-GEMM outputs, 256B aligned
    unsigned short* EAr  = (unsigned short*)(((uintptr_t)(posS + E) + 255) & ~(uintptr_t)255);
    const int nt256 = (E + 255) / 256;
    const long Epad = (long)nt256 * 256;
    unsigned short* EAro = EAr + Epad * 256;   // Epad*32 u16

    const int* row = edge_index;
    const int* col = edge_index + E;

    const int nb64 = (N + 63) / 64;
    const int eb64 = (E + 63) / 64;
    const int eb256 = (E + 255) / 256;
    const int nb256 = (N + 255) / 256;

    // ---- counting sort of edges by destination ----
    hipMemsetAsync(cursor, 0, (size_t)(N + 1) * sizeof(int), stream);
    k_hist<<<eb256, 256, 0, stream>>>(col, cursor, E);
    k_scan<<<1, 1024, 0, stream>>>(cursor, N);
    k_scatter<<<eb256, 256, 0, stream>>>(row, col, cursor, rowS, colS, posS, E);

    // ---- weight prep ----
    cvt_bf16<<<(256 * 384 + 255) / 256, 256, 0, stream>>>(edge_W0, eW0h, 256 * 384);
    cvt_bf16<<<(256 * 384 + 255) / 256, 256, 0, stream>>>(edge_W1, eW1h, 256 * 384);
    cvt_bf16<<<(32 * 384 + 255) / 256, 256, 0, stream>>>(edge_Wo, eWoh, 32 * 384);
    cvt_bf16<<<(256 * 256 + 255) / 256, 256, 0, stream>>>(node_W0, nW0h, 256 * 256);
    cvt_bf16<<<(256 * 256 + 255) / 256, 256, 0, stream>>>(node_W1, nW1h, 256 * 256);
    cvt_bf16<<<(32 * 768 + 255) / 256, 256, 0, stream>>>(node_Wo, nWoh, 32 * 768);
    pack_kan_bf16<<<(256 * 256 + 255) / 256, 256, 0, stream>>>(base_W0, spline_W0, Wc0h, 256 * 256);
    pack_kan_bf16<<<(256 * 256 + 255) / 256, 256, 0, stream>>>(base_W1, spline_W1, Wc1h, 256 * 256);
    pack_kan_f32<<<(32 * 32 + 255) / 256, 256, 0, stream>>>(base_Wo, spline_Wo, Wco, 32 * 32);

    // ---- edge GEMM D1: W0 + Wo (one pass over EA) ----
    ea_gemm<true><<<eb64, 256, 0, stream>>>(
        edge_attr, eW0h, edge_b0, eWoh, edge_bo, posS, EAr, EAro, E);

    // ---- layer 0 ----
    hipMemsetAsync(agg, 0, (size_t)N * 256 * sizeof(float), stream);
    node_mfma<256><<<nb64, 256, 0, stream>>>(x, nW0h, node_b0, xt, N);
    msg256<<<eb64, 256, 0, stream>>>(EAr, xt, rowS, colS, agg, E);
    kan_mfma256<<<nb64, 256, 0, stream>>>(agg, Wc0h, h0, N);

    // ---- edge GEMM D2: W1 (reuses EAr buffer) ----
    ea_gemm<false><<<eb64, 256, 0, stream>>>(
        edge_attr, eW1h, edge_b1, eWoh, edge_bo, posS, EAr, EAro, E);

    // ---- layer 1 ----
    hipMemsetAsync(agg, 0, (size_t)N * 256 * sizeof(float), stream);
    node_mfma<256><<<nb64, 256, 0, stream>>>(h0, nW1h, node_b1, xt, N);
    msg256<<<eb64, 256, 0, stream>>>(EAr, xt, rowS, colS, agg, E);
    kan_mfma256<<<nb64, 256, 0, stream>>>(agg, Wc1h, h1, N);

    // ---- output layer ----
    hipMemsetAsync(agg, 0, (size_t)N * 32 * sizeof(float), stream);
    node_cat_mfma<<<nb256, 256, 0, stream>>>(x, h0, h1, nWoh, node_bo, xt, N);
    msg32<<<eb256, 256, 0, stream>>>(EAro, xt, rowS, colS, agg, E);
    kan_gemm32<<<nb64, 256, 0, stream>>>(agg, Wco, out, N);
}

// Round 5
// 1643.394 us; speedup vs baseline: 1.3673x; 1.1037x over previous
//
#include <hip/hip_runtime.h>

// ---------------------------------------------------------------------------
// GCKAN (3 layers) on MI355X — round 7.
// ea_gemm2: ONE pass over EA computes all three edge GEMMs (W0, W1, Wo),
// with counted s_waitcnt vmcnt(2) + raw s_barrier per K-step (T3/T4) so
// A-prefetch loads stay in flight across the barrier. XOR-swizzled A rows.
// ---------------------------------------------------------------------------

typedef __attribute__((ext_vector_type(4))) float f32x4;
typedef __attribute__((ext_vector_type(8))) short bf16x8;
typedef __attribute__((ext_vector_type(8))) unsigned short u16x8;
typedef __attribute__((ext_vector_type(4))) unsigned short u16x4;

__device__ __forceinline__ unsigned short f2bf(float f) {
    union { float f; unsigned u; } v; v.f = f;
    unsigned r = v.u + 0x7FFFu + ((v.u >> 16) & 1u);
    return (unsigned short)(r >> 16);
}

__device__ __forceinline__ float bf2f(unsigned short u) {
    union { unsigned u; float f; } v; v.u = ((unsigned)u) << 16;
    return v.f;
}

__device__ __forceinline__ float siluf(float x) {
    return x / (1.0f + __expf(-x));
}

// async global->LDS, 16B per lane; dest must be WAVE-UNIFORM (HW adds lane*16).
__device__ __forceinline__ void gl16(const void* g, void* l) {
    __builtin_amdgcn_global_load_lds(
        (const __attribute__((address_space(1))) unsigned*)g,
        (__attribute__((address_space(3))) unsigned*)l, 16, 0, 0);
}

// Expand scalar x -> 8 channels [silu, B0..B6]; cubic B-spline on uniform
// knots t_i = 0.5 i - 2.5 (matches reference Cox-de Boor exactly).
__device__ __forceinline__ void expand8(float x, float* o8) {
    float b[10];
#pragma unroll
    for (int i = 0; i < 10; ++i) {
        float ti = 0.5f * i - 2.5f;
        b[i] = (x >= ti && x < ti + 0.5f) ? 1.0f : 0.0f;
    }
#pragma unroll
    for (int j = 1; j <= 3; ++j) {
        float inv = 2.0f / (float)j;
#pragma unroll
        for (int i = 0; i < 10 - j; ++i) {
            float ti = 0.5f * i - 2.5f;
            float tj = 0.5f * (i + j + 1) - 2.5f;
            b[i] = (x - ti) * inv * b[i] + (tj - x) * inv * b[i + 1];
        }
    }
    o8[0] = siluf(x);
#pragma unroll
    for (int c = 0; c < 7; ++c) o8[c + 1] = b[c];
}

// ---------------------------------------------------------------------------
// Edge counting sort by destination (col). posS[i] = sorted position of edge i.
// ---------------------------------------------------------------------------
__global__ __launch_bounds__(256) void k_hist(
    const int* __restrict__ col, int* __restrict__ cnt, int E) {
    int i = blockIdx.x * 256 + threadIdx.x;
    if (i < E) atomicAdd(&cnt[col[i]], 1);
}

__global__ __launch_bounds__(1024) void k_scan(int* __restrict__ c, int N) {
    __shared__ int wsum[16];
    __shared__ int ctot;
    const int t = threadIdx.x;
    const int lane = t & 63, wid = t >> 6;
    int carry = 0;
    for (int base = 0; base < N; base += 1024) {
        int i = base + t;
        int v0 = (i < N) ? c[i] : 0;
        int v = v0;
#pragma unroll
        for (int off = 1; off < 64; off <<= 1) {
            int n = __shfl_up(v, (unsigned)off, 64);
            if (lane >= off) v += n;
        }
        if (lane == 63) wsum[wid] = v;
        __syncthreads();
        if (t < 16) {
            int s = wsum[t], sv = s;
#pragma unroll
            for (int off = 1; off < 16; off <<= 1) {
                int n = __shfl_up(sv, (unsigned)off, 16);
                if (t >= off) sv += n;
            }
            wsum[t] = sv - s;
            if (t == 15) ctot = sv;
        }
        __syncthreads();
        if (i < N) c[i] = carry + wsum[wid] + v - v0;
        carry += ctot;
        __syncthreads();
    }
}

__global__ __launch_bounds__(256) void k_scatter(
    const int* __restrict__ row, const int* __restrict__ col,
    int* __restrict__ cursor, int* __restrict__ rowS,
    int* __restrict__ colS, int* __restrict__ posS, int E) {
    int i = blockIdx.x * 256 + threadIdx.x;
    if (i < E) {
        int c = col[i];
        int p = atomicAdd(&cursor[c], 1);
        rowS[p] = row[i];
        colS[p] = c;
        posS[i] = p;
    }
}

// ---------------------------------------------------------------------------
// Combined edge GEMM: one pass over EA(E,384) computing up to three panels:
//   O0 = EA@W0^T + b0 (256), [TWO] O1 = EA@W1^T + b1 (256),
//   [WITH_O, waves 0-1] Oo = EA@Wo^T + bo (32).
// bf16 rows stored at SORTED positions. Tile 64 edges, 4 waves.
// Counted vmcnt + raw barrier: A reg-prefetch stays in flight across sync.
// ---------------------------------------------------------------------------
template <bool TWO, bool WITH_O>
__global__ __launch_bounds__(256, 2) void ea_gemm2(
    const float* __restrict__ EA,
    const unsigned short* __restrict__ W0, const float* __restrict__ b0,
    const unsigned short* __restrict__ W1, const float* __restrict__ b1,
    const unsigned short* __restrict__ Wo, const float* __restrict__ bo,
    const int* __restrict__ posS,
    unsigned short* __restrict__ O0, unsigned short* __restrict__ O1,
    unsigned short* __restrict__ Oo, int E) {
    // A: 2x4KB @0 ; B0: 2x16KB @8192 ; [TWO] B1: 2x16KB @40960 ;
    // [WITH_O] Bo: 2x2KB @ (TWO?73728:40960)
    constexpr int BOOFF = TWO ? 73728 : 40960;
    constexpr int SMEMSZ = BOOFF + (WITH_O ? 4096 : 0);
    __shared__ __align__(16) char smem[SMEMSZ];
    __shared__ int pos_s[64];

    const int tid = threadIdx.x;
    const int wv = tid >> 6, lane = tid & 63;
    const int l15 = lane & 15, l4 = lane >> 4;
    const long m0 = (long)blockIdx.x * 64;

    f32x4 acc0[4][4] = {};
    f32x4 acc1[4][4] = {};
    f32x4 acco[4] = {};

    const int sr = tid >> 2, sg = tid & 3;
    const long arow = m0 + sr;
    const bool aok = arow < E;
    const float* aptr = EA + arow * 384 + sg * 8;
    const int awoff = sg * 1024 + ((sr ^ (sg << 2))) * 16;   // XOR-swizzled row

    const unsigned short* w0p = W0 + (long)tid * 384;
    const unsigned short* w1p = TWO ? (W1 + (long)tid * 384) : W0;
    const unsigned short* wop = Wo;
    if (WITH_O) {
        int o = wv * 1024 + lane * 16;
        int g = o >> 9, brow = (o >> 4) & 31;
        wop = Wo + (long)brow * 384 + g * 8;
    }

    if (tid < 64) { long p = m0 + tid; pos_s[tid] = (p < E) ? posS[p] : -1; }

#define ISSUE_B(IT, BUF)                                                       \
    {                                                                          \
        _Pragma("unroll")                                                      \
        for (int g = 0; g < 4; ++g)                                            \
            gl16(w0p + (IT) * 32 + g * 8,                                      \
                 smem + 8192 + (BUF) * 16384 + g * 4096 + wv * 1024);          \
        if (TWO) {                                                             \
            _Pragma("unroll")                                                  \
            for (int g = 0; g < 4; ++g)                                        \
                gl16(w1p + (IT) * 32 + g * 8,                                  \
                     smem + 40960 + (BUF) * 16384 + g * 4096 + wv * 1024);     \
        }                                                                      \
        if (WITH_O && wv < 2)                                                  \
            gl16(wop + (IT) * 32, smem + BOOFF + (BUF) * 2048 + wv * 1024);    \
        __builtin_amdgcn_sched_barrier(0);                                     \
    }

#define WRITE_A(BUF)                                                           \
    {                                                                          \
        u16x8 rr = {};                                                         \
        if (aok) {                                                             \
            rr[0] = f2bf(a0v.x); rr[1] = f2bf(a0v.y);                          \
            rr[2] = f2bf(a0v.z); rr[3] = f2bf(a0v.w);                          \
            rr[4] = f2bf(a1v.x); rr[5] = f2bf(a1v.y);                          \
            rr[6] = f2bf(a1v.z); rr[7] = f2bf(a1v.w);                          \
        }                                                                      \
        *(u16x8*)(smem + (BUF) * 4096 + awoff) = rr;                           \
        __builtin_amdgcn_sched_barrier(0);                                     \
    }

    // ---- prologue: B(0) gl16 -> buf0; A(0) -> LDS buf0; A(1) -> regs ----
    ISSUE_B(0, 0);
    float4 a0v = make_float4(0.f, 0.f, 0.f, 0.f);
    float4 a1v = make_float4(0.f, 0.f, 0.f, 0.f);
    if (aok) { a0v = *(const float4*)(aptr); a1v = *(const float4*)(aptr + 4); }
    WRITE_A(0);
    if (aok) { a0v = *(const float4*)(aptr + 32); a1v = *(const float4*)(aptr + 36); }
    __builtin_amdgcn_sched_barrier(0);

#pragma unroll
    for (int it = 0; it < 12; ++it) {
        // entry: buf(it) staged modulo vmcnt; leave only private A loads (2).
        if (it == 11) asm volatile("s_waitcnt vmcnt(0)" ::: "memory");
        else          asm volatile("s_waitcnt vmcnt(2)" ::: "memory");
        asm volatile("s_waitcnt lgkmcnt(0)" ::: "memory");
        __builtin_amdgcn_s_barrier();
        __builtin_amdgcn_sched_barrier(0);
        const int buf = it & 1, nbf = buf ^ 1;
        if (it < 11) {
            ISSUE_B(it + 1, nbf);
            WRITE_A(nbf);                       // compiler waits old A loads
            if (it < 10) {
                if (aok) {
                    a0v = *(const float4*)(aptr + (it + 2) * 32);
                    a1v = *(const float4*)(aptr + (it + 2) * 32 + 4);
                }
                __builtin_amdgcn_sched_barrier(0);
            }
        }
        bf16x8 af[4];
#pragma unroll
        for (int mi = 0; mi < 4; ++mi)
            af[mi] = *(const bf16x8*)(smem + buf * 4096 + l4 * 1024 +
                                      (((mi * 16 + l15) ^ (l4 << 2))) * 16);
        {
            bf16x8 bf0[4];
#pragma unroll
            for (int nj = 0; nj < 4; ++nj)
                bf0[nj] = *(const bf16x8*)(smem + 8192 + buf * 16384 + l4 * 4096 +
                                           (wv * 64 + nj * 16 + l15) * 16);
#pragma unroll
            for (int mi = 0; mi < 4; ++mi)
#pragma unroll
                for (int nj = 0; nj < 4; ++nj)
                    acc0[mi][nj] = __builtin_amdgcn_mfma_f32_16x16x32_bf16(
                        af[mi], bf0[nj], acc0[mi][nj], 0, 0, 0);
        }
        if (TWO) {
            bf16x8 bf1[4];
#pragma unroll
            for (int nj = 0; nj < 4; ++nj)
                bf1[nj] = *(const bf16x8*)(smem + 40960 + buf * 16384 + l4 * 4096 +
                                           (wv * 64 + nj * 16 + l15) * 16);
#pragma unroll
            for (int mi = 0; mi < 4; ++mi)
#pragma unroll
                for (int nj = 0; nj < 4; ++nj)
                    acc1[mi][nj] = __builtin_amdgcn_mfma_f32_16x16x32_bf16(
                        af[mi], bf1[nj], acc1[mi][nj], 0, 0, 0);
        }
        if (WITH_O && wv < 2) {
            bf16x8 bov = *(const bf16x8*)(smem + BOOFF + buf * 2048 + l4 * 512 +
                                          (wv * 16 + l15) * 16);
#pragma unroll
            for (int mi = 0; mi < 4; ++mi)
                acco[mi] = __builtin_amdgcn_mfma_f32_16x16x32_bf16(
                    af[mi], bov, acco[mi], 0, 0, 0);
        }
    }
#undef ISSUE_B
#undef WRITE_A

    // ---- epilogue: bias + bf16 store at sorted positions ----
    const int nb2 = wv * 64;
    float bs0[4];
#pragma unroll
    for (int nj = 0; nj < 4; ++nj) bs0[nj] = b0[nb2 + nj * 16 + l15];
#pragma unroll
    for (int mi = 0; mi < 4; ++mi) {
#pragma unroll
        for (int r = 0; r < 4; ++r) {
            int edge = mi * 16 + l4 * 4 + r;
            int pos = pos_s[edge];
            if (pos >= 0) {
                unsigned short* dst = O0 + (long)pos * 256 + nb2 + l15;
#pragma unroll
                for (int nj = 0; nj < 4; ++nj)
                    dst[nj * 16] = f2bf(acc0[mi][nj][r] + bs0[nj]);
            }
        }
    }
    if (TWO) {
        float bs1[4];
#pragma unroll
        for (int nj = 0; nj < 4; ++nj) bs1[nj] = b1[nb2 + nj * 16 + l15];
#pragma unroll
        for (int mi = 0; mi < 4; ++mi) {
#pragma unroll
            for (int r = 0; r < 4; ++r) {
                int edge = mi * 16 + l4 * 4 + r;
                int pos = pos_s[edge];
                if (pos >= 0) {
                    unsigned short* dst = O1 + (long)pos * 256 + nb2 + l15;
#pragma unroll
                    for (int nj = 0; nj < 4; ++nj)
                        dst[nj * 16] = f2bf(acc1[mi][nj][r] + bs1[nj]);
                }
            }
        }
    }
    if (WITH_O && wv < 2) {
        float bso = bo[wv * 16 + l15];
#pragma unroll
        for (int mi = 0; mi < 4; ++mi) {
#pragma unroll
            for (int r = 0; r < 4; ++r) {
                int edge = mi * 16 + l4 * 4 + r;
                int pos = pos_s[edge];
                if (pos >= 0)
                    Oo[(long)pos * 32 + wv * 16 + l15] = f2bf(acco[mi][r] + bso);
            }
        }
    }
}

// ---------------------------------------------------------------------------
// Message+reduce, N=256: per 64-sorted-edge tile, thread owns one column,
// accumulates runs of equal dest in registers; plain store for interior runs.
// ---------------------------------------------------------------------------
__global__ __launch_bounds__(256) void msg256(
    const unsigned short* __restrict__ EAr, const unsigned short* __restrict__ XT,
    const int* __restrict__ rowS, const int* __restrict__ colS,
    float* __restrict__ AGG, int E) {
    __shared__ __align__(16) unsigned short eas[64][256];   // 32KB
    __shared__ int rows_s[64];
    __shared__ int cols_s[64];
    const int tid = threadIdx.x;
    const int wv = tid >> 6, lane = tid & 63;
    const long m0 = (long)blockIdx.x * 64;

    const char* src = (const char*)(EAr + m0 * 256);
#pragma unroll
    for (int j = 0; j < 8; ++j)
        gl16(src + (j * 4 + wv) * 1024 + lane * 16,
             ((char*)&eas[0][0]) + (j * 4 + wv) * 1024);
    if (tid < 64) {
        long p = m0 + tid;
        cols_s[tid] = (p < E) ? colS[p] : -1;
        rows_s[tid] = (p < E) ? rowS[p] : 0;
    }
    __syncthreads();

    const int c = tid;            // 0..255
    float sum = 0.f;
    int cur = cols_s[0];
    int runstart = 0;
#pragma unroll 1
    for (int g = 0; g < 8; ++g) {
        float xv[8];
#pragma unroll
        for (int j = 0; j < 8; ++j)
            xv[j] = bf2f(XT[(long)rows_s[g * 8 + j] * 256 + c]);
#pragma unroll
        for (int j = 0; j < 8; ++j) {
            int e = g * 8 + j;
            int cc = cols_s[e];
            if (cc != cur) {                 // uniform branch (cols_s broadcast)
                if (cur >= 0) {
                    float* dst = AGG + (long)cur * 256 + c;
                    if (runstart > 0) *dst = sum;     // run complete in-tile
                    else atomicAdd(dst, sum);         // may continue prev tile
                }
                cur = cc; runstart = e; sum = 0.f;
            }
            sum += bf2f(eas[e][c]) * xv[j];
        }
    }
    if (cur >= 0) {                          // touches tile end -> atomic
        atomicAdd(AGG + (long)cur * 256 + c, sum);
    }
}

// ---------------------------------------------------------------------------
// Message+reduce, N=32 (output layer): 256-edge tile, thread = (sub, col).
// ---------------------------------------------------------------------------
__global__ __launch_bounds__(256) void msg32(
    const unsigned short* __restrict__ EAro, const unsigned short* __restrict__ XT,
    const int* __restrict__ rowS, const int* __restrict__ colS,
    float* __restrict__ AGG, int E) {
    __shared__ __align__(16) unsigned short eas[256][32];   // 16KB
    __shared__ int rows_s[256];
    __shared__ int cols_s[256];
    const int tid = threadIdx.x;
    const int wv = tid >> 6, lane = tid & 63;
    const long m0 = (long)blockIdx.x * 256;

    const char* src = (const char*)(EAro + m0 * 32);
#pragma unroll
    for (int j = 0; j < 4; ++j)
        gl16(src + (j * 4 + wv) * 1024 + lane * 16,
             ((char*)&eas[0][0]) + (j * 4 + wv) * 1024);
    {
        long p = m0 + tid;
        cols_s[tid] = (p < E) ? colS[p] : -1;
        rows_s[tid] = (p < E) ? rowS[p] : 0;
    }
    __syncthreads();

    const int c = tid & 31, s = tid >> 5;    // 8 sub-tiles of 32 edges
    const int e0 = s * 32;
    float sum = 0.f;
    int cur = cols_s[e0];
    int runstart = e0;
#pragma unroll 1
    for (int g = 0; g < 4; ++g) {
        float xv[8];
#pragma unroll
        for (int j = 0; j < 8; ++j)
            xv[j] = bf2f(XT[(long)rows_s[e0 + g * 8 + j] * 32 + c]);
#pragma unroll
        for (int j = 0; j < 8; ++j) {
            int e = e0 + g * 8 + j;
            int cc = cols_s[e];
            if (cc != cur) {
                if (cur >= 0) {
                    float* dst = AGG + (long)cur * 32 + c;
                    if (runstart > 0 && cols_s[runstart - 1] != cur) *dst = sum;
                    else atomicAdd(dst, sum);
                }
                cur = cc; runstart = e; sum = 0.f;
            }
            sum += bf2f(eas[e][c]) * xv[j];
        }
    }
    if (cur >= 0) {
        int eend = e0 + 32;
        float* dst = AGG + (long)cur * 32 + c;
        bool oks = (runstart > 0 && cols_s[runstart - 1] != cur);
        bool oke = (eend < 256 && cols_s[eend] != cur);
        if (oks && oke) *dst = sum;
        else atomicAdd(dst, sum);
    }
}

// ---------------------------------------------------------------------------
// Node GEMM N=256: Y(bf16) = X(M,K)@Wh(256,K)^T + bias.
// ---------------------------------------------------------------------------
template <int K>
__global__ __launch_bounds__(256) void node_mfma(
    const float* __restrict__ X, const unsigned short* __restrict__ Wh,
    const float* __restrict__ bias, unsigned short* __restrict__ Y, int M) {
    __shared__ __align__(16) unsigned short As[4][64][8];
    __shared__ __align__(16) unsigned short Bs[4][256][8];
    const int tid = threadIdx.x;
    const int wv = tid >> 6, lane = tid & 63;
    const int l15 = lane & 15, l4 = lane >> 4;
    const long m0 = (long)blockIdx.x * 64;
    f32x4 acc[4][4] = {};

    const int sr = tid >> 2, sg = tid & 3;
    const long arow = m0 + sr;
    const float* aptr = X + arow * K + sg * 8;
    const bool aok = arow < M;
    const unsigned short* bptr = Wh + (long)tid * K;

    for (int it = 0; it < K / 32; ++it) {
        const int k0 = it * 32;
        u16x8 ap = {};
        if (aok) {
            float4 v0 = *(const float4*)(aptr + k0);
            float4 v1 = *(const float4*)(aptr + k0 + 4);
            ap[0] = f2bf(v0.x); ap[1] = f2bf(v0.y); ap[2] = f2bf(v0.z); ap[3] = f2bf(v0.w);
            ap[4] = f2bf(v1.x); ap[5] = f2bf(v1.y); ap[6] = f2bf(v1.z); ap[7] = f2bf(v1.w);
        }
        u16x8 b0 = *(const u16x8*)(bptr + k0);
        u16x8 b1 = *(const u16x8*)(bptr + k0 + 8);
        u16x8 b2 = *(const u16x8*)(bptr + k0 + 16);
        u16x8 b3 = *(const u16x8*)(bptr + k0 + 24);
        __syncthreads();
        *(u16x8*)&As[sg][sr][0] = ap;
        *(u16x8*)&Bs[0][tid][0] = b0;
        *(u16x8*)&Bs[1][tid][0] = b1;
        *(u16x8*)&Bs[2][tid][0] = b2;
        *(u16x8*)&Bs[3][tid][0] = b3;
        __syncthreads();
        bf16x8 af[4], bfv[4];
#pragma unroll
        for (int mi = 0; mi < 4; ++mi)
            af[mi] = *(const bf16x8*)&As[l4][mi * 16 + l15][0];
#pragma unroll
        for (int nj = 0; nj < 4; ++nj)
            bfv[nj] = *(const bf16x8*)&Bs[l4][wv * 64 + nj * 16 + l15][0];
#pragma unroll
        for (int mi = 0; mi < 4; ++mi)
#pragma unroll
            for (int nj = 0; nj < 4; ++nj)
                acc[mi][nj] = __builtin_amdgcn_mfma_f32_16x16x32_bf16(
                    af[mi], bfv[nj], acc[mi][nj], 0, 0, 0);
    }

    const int nb = wv * 64;
    float bs[4];
#pragma unroll
    for (int nj = 0; nj < 4; ++nj) bs[nj] = bias[nb + nj * 16 + l15];
#pragma unroll
    for (int mi = 0; mi < 4; ++mi) {
#pragma unroll
        for (int r = 0; r < 4; ++r) {
            long gm = m0 + mi * 16 + l4 * 4 + r;
            if (gm < M) {
#pragma unroll
                for (int nj = 0; nj < 4; ++nj)
                    Y[gm * 256 + nb + nj * 16 + l15] = f2bf(acc[mi][nj][r] + bs[nj]);
            }
        }
    }
}

// ---------------------------------------------------------------------------
// KAN linear N=256: Y = expand8(AGG)(M,2048) @ Wch(256,2048)^T. B-prefetch.
// ---------------------------------------------------------------------------
__global__ __launch_bounds__(256) void kan_mfma256(
    const float* __restrict__ AGG, const unsigned short* __restrict__ Wch,
    float* __restrict__ Y, int M) {
    __shared__ __align__(16) unsigned short As[4][64][8];
    __shared__ __align__(16) unsigned short Bs[4][256][8];
    const int tid = threadIdx.x;
    const int wv = tid >> 6, lane = tid & 63;
    const int l15 = lane & 15, l4 = lane >> 4;
    const long m0 = (long)blockIdx.x * 64;
    f32x4 acc[4][4] = {};

    const int srow = tid & 63, sg = tid >> 6;
    const long arow = m0 + srow;
    const bool aok = arow < M;
    const float* aptr = AGG + arow * 256 + sg;
    const unsigned short* bptr = Wch + (long)tid * 2048;

    float xv = aok ? aptr[0] : 0.f;
    u16x8 pb0 = *(const u16x8*)(bptr);
    u16x8 pb1 = *(const u16x8*)(bptr + 8);
    u16x8 pb2 = *(const u16x8*)(bptr + 16);
    u16x8 pb3 = *(const u16x8*)(bptr + 24);

    for (int it = 0; it < 64; ++it) {
        float e8[8];
        expand8(xv, e8);
        u16x8 ap;
#pragma unroll
        for (int c = 0; c < 8; ++c) ap[c] = f2bf(e8[c]);
        __syncthreads();
        *(u16x8*)&As[sg][srow][0] = ap;
        *(u16x8*)&Bs[0][tid][0] = pb0;
        *(u16x8*)&Bs[1][tid][0] = pb1;
        *(u16x8*)&Bs[2][tid][0] = pb2;
        *(u16x8*)&Bs[3][tid][0] = pb3;
        __syncthreads();
        if (it < 63) {
            xv = aok ? aptr[(it + 1) * 4] : 0.f;
            const int k0 = (it + 1) * 32;
            pb0 = *(const u16x8*)(bptr + k0);
            pb1 = *(const u16x8*)(bptr + k0 + 8);
            pb2 = *(const u16x8*)(bptr + k0 + 16);
            pb3 = *(const u16x8*)(bptr + k0 + 24);
        }
        bf16x8 af[4], bfv[4];
#pragma unroll
        for (int mi = 0; mi < 4; ++mi)
            af[mi] = *(const bf16x8*)&As[l4][mi * 16 + l15][0];
#pragma unroll
        for (int nj = 0; nj < 4; ++nj)
            bfv[nj] = *(const bf16x8*)&Bs[l4][wv * 64 + nj * 16 + l15][0];
#pragma unroll
        for (int mi = 0; mi < 4; ++mi)
#pragma unroll
            for (int nj = 0; nj < 4; ++nj)
                acc[mi][nj] = __builtin_amdgcn_mfma_f32_16x16x32_bf16(
                    af[mi], bfv[nj], acc[mi][nj], 0, 0, 0);
    }

    const int nb = wv * 64;
#pragma unroll
    for (int mi = 0; mi < 4; ++mi) {
#pragma unroll
        for (int r = 0; r < 4; ++r) {
            long gm = m0 + mi * 16 + l4 * 4 + r;
            if (gm < M) {
#pragma unroll
                for (int nj = 0; nj < 4; ++nj)
                    Y[gm * 256 + nb + nj * 16 + l15] = acc[mi][nj][r];
            }
        }
    }
}

// ---------------------------------------------------------------------------
// Node GEMM for concat input, N=32: Y(bf16) = [x|h0|h1](M,768)@Wh(32,768)^T+b.
// ---------------------------------------------------------------------------
__global__ __launch_bounds__(256) void node_cat_mfma(
    const float* __restrict__ X, const float* __restrict__ H0,
    const float* __restrict__ H1, const unsigned short* __restrict__ Wh,
    const float* __restrict__ bias, unsigned short* __restrict__ Y, int M) {
    __shared__ __align__(16) unsigned short As[4][256][8];
    __shared__ __align__(16) unsigned short Bs[4][32][8];
    const int tid = threadIdx.x;
    const int wv = tid >> 6, lane = tid & 63;
    const int l15 = lane & 15, l4 = lane >> 4;
    const long m0 = (long)blockIdx.x * 256;
    f32x4 acc[4][2] = {};

    const int sr = tid >> 3;
    const int sq = (tid & 7) * 4;
    const int sg2 = sq >> 3, so2 = sq & 7;

    for (int it = 0; it < 24; ++it) {
        const int k0 = it * 32;
        const float* src = (it < 8) ? X : (it < 16) ? H0 : H1;
        const int kk = k0 & 255;
        float4 va[8];
#pragma unroll
        for (int j = 0; j < 8; ++j) {
            long r_ = m0 + j * 32 + sr;
            va[j] = (r_ < M) ? *(const float4*)(src + r_ * 256 + kk + sq)
                             : make_float4(0.f, 0.f, 0.f, 0.f);
        }
        u16x8 bv = {};
        if (tid < 128)
            bv = *(const u16x8*)(Wh + (long)(tid >> 2) * 768 + k0 + (tid & 3) * 8);
        __syncthreads();
#pragma unroll
        for (int j = 0; j < 8; ++j) {
            u16x4 ap;
            ap[0] = f2bf(va[j].x); ap[1] = f2bf(va[j].y);
            ap[2] = f2bf(va[j].z); ap[3] = f2bf(va[j].w);
            *(u16x4*)&As[sg2][j * 32 + sr][so2] = ap;
        }
        if (tid < 128) *(u16x8*)&Bs[tid & 3][tid >> 2][0] = bv;
        __syncthreads();
        bf16x8 af[4], bfv[2];
#pragma unroll
        for (int mi = 0; mi < 4; ++mi)
            af[mi] = *(const bf16x8*)&As[l4][wv * 64 + mi * 16 + l15][0];
#pragma unroll
        for (int nj = 0; nj < 2; ++nj)
            bfv[nj] = *(const bf16x8*)&Bs[l4][nj * 16 + l15][0];
#pragma unroll
        for (int mi = 0; mi < 4; ++mi)
#pragma unroll
            for (int nj = 0; nj < 2; ++nj)
                acc[mi][nj] = __builtin_amdgcn_mfma_f32_16x16x32_bf16(
                    af[mi], bfv[nj], acc[mi][nj], 0, 0, 0);
    }

#pragma unroll
    for (int mi = 0; mi < 4; ++mi) {
#pragma unroll
        for (int r = 0; r < 4; ++r) {
            long gm = m0 + wv * 64 + mi * 16 + l4 * 4 + r;
            if (gm < M) {
#pragma unroll
                for (int nj = 0; nj < 2; ++nj) {
                    int o = nj * 16 + l15;
                    Y[gm * 32 + o] = f2bf(acc[mi][nj][r] + bias[o]);
                }
            }
        }
    }
}

// ---------------------------------------------------------------------------
// Small f32 KAN for output layer (M x 32 -> M x 32).
// ---------------------------------------------------------------------------
__global__ __launch_bounds__(256) void kan_gemm32(
    const float* __restrict__ AGG, const float* __restrict__ Wc,
    float* __restrict__ Y, int M) {
    __shared__ float As[64][36];
    __shared__ float Bs[32][36];
    const int tid = threadIdx.x;
    const int tx = tid & 15, ty = tid >> 4;
    const int m0 = blockIdx.x * 64;
    float acc[4][2] = {{0.f, 0.f}, {0.f, 0.f}, {0.f, 0.f}, {0.f, 0.f}};
    const int er = tid >> 2, ef = tid & 3;
    const int em = m0 + er;
    for (int ic = 0; ic < 32; ic += 4) {
        float xv = (em < M) ? AGG[(long)em * 32 + ic + ef] : 0.f;
        float e8[8];
        expand8(xv, e8);
        *(float4*)&As[er][ef * 8] = make_float4(e8[0], e8[1], e8[2], e8[3]);
        *(float4*)&As[er][ef * 8 + 4] = make_float4(e8[4], e8[5], e8[6], e8[7]);
        {
            int o = tid >> 3, k4 = (tid & 7) * 4;
            *(float4*)&Bs[o][k4] = *(const float4*)&Wc[(long)o * 256 + ic * 8 + k4];
        }
        __syncthreads();
#pragma unroll
        for (int kk = 0; kk < 32; ++kk) {
            float a_[4], b_[2];
#pragma unroll
            for (int i = 0; i < 4; ++i) a_[i] = As[ty * 4 + i][kk];
#pragma unroll
            for (int j = 0; j < 2; ++j) b_[j] = Bs[tx * 2 + j][kk];
#pragma unroll
            for (int i = 0; i < 4; ++i)
#pragma unroll
                for (int j = 0; j < 2; ++j) acc[i][j] = fmaf(a_[i], b_[j], acc[i][j]);
        }
        __syncthreads();
    }
#pragma unroll
    for (int i = 0; i < 4; ++i) {
        int gm = m0 + ty * 4 + i;
        if (gm >= M) continue;
#pragma unroll
        for (int j = 0; j < 2; ++j) Y[(long)gm * 32 + tx * 2 + j] = acc[i][j];
    }
}

// ---------------------------------------------------------------------------
// Weight prep
// ---------------------------------------------------------------------------
__global__ __launch_bounds__(256) void cvt_bf16(
    const float* __restrict__ s, unsigned short* __restrict__ d, int n) {
    int i = blockIdx.x * 256 + threadIdx.x;
    if (i < n) d[i] = f2bf(s[i]);
}

__global__ __launch_bounds__(256) void pack_kan_bf16(
    const float* __restrict__ baseW, const float* __restrict__ splineW,
    unsigned short* __restrict__ Wc, int n) {
    int idx = blockIdx.x * 256 + threadIdx.x;
    if (idx >= n) return;
    unsigned short* dst = Wc + (long)idx * 8;
    dst[0] = f2bf(baseW[idx]);
    const float* sw = splineW + (long)idx * 7;
#pragma unroll
    for (int c = 0; c < 7; ++c) dst[1 + c] = f2bf(sw[c]);
}

__global__ __launch_bounds__(256) void pack_kan_f32(
    const float* __restrict__ baseW, const float* __restrict__ splineW,
    float* __restrict__ Wc, int n) {
    int idx = blockIdx.x * 256 + threadIdx.x;
    if (idx >= n) return;
    float* dst = Wc + (long)idx * 8;
    dst[0] = baseW[idx];
    const float* sw = splineW + (long)idx * 7;
#pragma unroll
    for (int c = 0; c < 7; ++c) dst[1 + c] = sw[c];
}

// ---------------------------------------------------------------------------
extern "C" void kernel_launch(void* const* d_in, const int* in_sizes, int n_in,
                              void* d_out, int out_size, void* d_ws, size_t ws_size,
                              hipStream_t stream) {
    const float* x          = (const float*)d_in[0];
    const int*   edge_index = (const int*)d_in[1];
    const float* edge_attr  = (const float*)d_in[2];
    const float* node_W0 = (const float*)d_in[3];
    const float* node_b0 = (const float*)d_in[4];
    const float* edge_W0 = (const float*)d_in[5];
    const float* edge_b0 = (const float*)d_in[6];
    const float* base_W0 = (const float*)d_in[7];
    const float* spline_W0 = (const float*)d_in[8];
    const float* node_W1 = (const float*)d_in[9];
    const float* node_b1 = (const float*)d_in[10];
    const float* edge_W1 = (const float*)d_in[11];
    const float* edge_b1 = (const float*)d_in[12];
    const float* base_W1 = (const float*)d_in[13];
    const float* spline_W1 = (const float*)d_in[14];
    const float* node_Wo = (const float*)d_in[15];
    const float* node_bo = (const float*)d_in[16];
    const float* edge_Wo = (const float*)d_in[17];
    const float* edge_bo = (const float*)d_in[18];
    const float* base_Wo = (const float*)d_in[19];
    const float* spline_Wo = (const float*)d_in[20];
    float* out = (float*)d_out;

    const int N = in_sizes[0] / 256;
    const int E = in_sizes[1] / 2;

    float* ws  = (float*)d_ws;
    unsigned short* xt = (unsigned short*)ws;  // bf16 XT (slot sized N*256 f32)
    float* agg = ws + (long)N * 256;           // N*256 f32
    float* h0  = agg + (long)N * 256;
    float* h1  = h0 + (long)N * 256;
    float* Wco = h1 + (long)N * 256;           // 32*256 f32
    unsigned short* Wc0h = (unsigned short*)(Wco + 32 * 256);
    unsigned short* Wc1h = Wc0h + 256 * 2048;
    unsigned short* eW0h = Wc1h + 256 * 2048;
    unsigned short* eW1h = eW0h + 256 * 384;
    unsigned short* eWoh = eW1h + 256 * 384;
    unsigned short* nW0h = eWoh + 32 * 384;
    unsigned short* nW1h = nW0h + 256 * 256;
    unsigned short* nWoh = nW1h + 256 * 256;   // 32*768
    int* cursor = (int*)(nWoh + 32 * 768);     // N+1
    int* rowS   = cursor + (N + 1);
    int* colS   = rowS + E;
    int* posS   = colS + E;
    unsigned short* EAr0 = (unsigned short*)(((uintptr_t)(posS + E) + 255) & ~(uintptr_t)255);
    const int nt256 = (E + 255) / 256;
    const long Epad = (long)nt256 * 256;
    unsigned short* EAr1 = EAr0 + Epad * 256;

    // TWO-panel mode needs EAr0 + EAr1 + EAro
    const size_t need2 = (size_t)((char*)(EAr1 + Epad * 256 + Epad * 32) - (char*)d_ws);
    const bool two = ws_size >= need2;
    unsigned short* EAro = two ? (EAr1 + Epad * 256) : (EAr0 + Epad * 256);

    const int* row = edge_index;
    const int* col = edge_index + E;

    const int nb64 = (N + 63) / 64;
    const int eb64 = (E + 63) / 64;
    const int eb256 = (E + 255) / 256;
    const int nb256 = (N + 255) / 256;

    // ---- counting sort of edges by destination ----
    hipMemsetAsync(cursor, 0, (size_t)(N + 1) * sizeof(int), stream);
    k_hist<<<eb256, 256, 0, stream>>>(col, cursor, E);
    k_scan<<<1, 1024, 0, stream>>>(cursor, N);
    k_scatter<<<eb256, 256, 0, stream>>>(row, col, cursor, rowS, colS, posS, E);

    // ---- weight prep ----
    cvt_bf16<<<(256 * 384 + 255) / 256, 256, 0, stream>>>(edge_W0, eW0h, 256 * 384);
    cvt_bf16<<<(256 * 384 + 255) / 256, 256, 0, stream>>>(edge_W1, eW1h, 256 * 384);
    cvt_bf16<<<(32 * 384 + 255) / 256, 256, 0, stream>>>(edge_Wo, eWoh, 32 * 384);
    cvt_bf16<<<(256 * 256 + 255) / 256, 256, 0, stream>>>(node_W0, nW0h, 256 * 256);
    cvt_bf16<<<(256 * 256 + 255) / 256, 256, 0, stream>>>(node_W1, nW1h, 256 * 256);
    cvt_bf16<<<(32 * 768 + 255) / 256, 256, 0, stream>>>(node_Wo, nWoh, 32 * 768);
    pack_kan_bf16<<<(256 * 256 + 255) / 256, 256, 0, stream>>>(base_W0, spline_W0, Wc0h, 256 * 256);
    pack_kan_bf16<<<(256 * 256 + 255) / 256, 256, 0, stream>>>(base_W1, spline_W1, Wc1h, 256 * 256);
    pack_kan_f32<<<(32 * 32 + 255) / 256, 256, 0, stream>>>(base_Wo, spline_Wo, Wco, 32 * 32);

    // ---- edge GEMMs ----
    if (two) {
        ea_gemm2<true, true><<<eb64, 256, 0, stream>>>(
            edge_attr, eW0h, edge_b0, eW1h, edge_b1, eWoh, edge_bo,
            posS, EAr0, EAr1, EAro, E);
    } else {
        ea_gemm2<false, true><<<eb64, 256, 0, stream>>>(
            edge_attr, eW0h, edge_b0, eW0h, edge_b0, eWoh, edge_bo,
            posS, EAr0, EAr0, EAro, E);
    }

    // ---- layer 0 ----
    hipMemsetAsync(agg, 0, (size_t)N * 256 * sizeof(float), stream);
    node_mfma<256><<<nb64, 256, 0, stream>>>(x, nW0h, node_b0, xt, N);
    msg256<<<eb64, 256, 0, stream>>>(EAr0, xt, rowS, colS, agg, E);
    kan_mfma256<<<nb64, 256, 0, stream>>>(agg, Wc0h, h0, N);

    // ---- layer 1 ----
    if (!two) {
        ea_gemm2<false, false><<<eb64, 256, 0, stream>>>(
            edge_attr, eW1h, edge_b1, eW1h, edge_b1, eWoh, edge_bo,
            posS, EAr0, EAr0, EAro, E);
    }
    hipMemsetAsync(agg, 0, (size_t)N * 256 * sizeof(float), stream);
    node_mfma<256><<<nb64, 256, 0, stream>>>(h0, nW1h, node_b1, xt, N);
    msg256<<<eb64, 256, 0, stream>>>(two ? EAr1 : EAr0, xt, rowS, colS, agg, E);
    kan_mfma256<<<nb64, 256, 0, stream>>>(agg, Wc1h, h1, N);

    // ---- output layer ----
    hipMemsetAsync(agg, 0, (size_t)N * 32 * sizeof(float), stream);
    node_cat_mfma<<<nb256, 256, 0, stream>>>(x, h0, h1, nWoh, node_bo, xt, N);
    msg32<<<eb256, 256, 0, stream>>>(EAro, xt, rowS, colS, agg, E);
    kan_gemm32<<<nb64, 256, 0, stream>>>(agg, Wco, out, N);
}